// Round 1
// baseline (335.883 us; speedup 1.0000x reference)
//
#include <hip/hip_runtime.h>

#define B_ 8
#define C_ 512
#define T_ 4096

typedef __attribute__((ext_vector_type(8))) __bf16 bf16x8;
typedef __attribute__((ext_vector_type(4))) float f32x4;

__device__ __forceinline__ unsigned short f2bf(float f) {
  unsigned int u = __float_as_uint(f);
  u += 0x7fffu + ((u >> 16) & 1u);   // RNE
  return (unsigned short)(u >> 16);
}
__device__ __forceinline__ float bf2f(unsigned short h) {
  return __uint_as_float(((unsigned int)h) << 16);
}

__device__ __forceinline__ void async16(unsigned short* ldsdst, const unsigned short* gsrc) {
  __builtin_amdgcn_global_load_lds(
      (__attribute__((address_space(1))) void*)(void*)const_cast<unsigned short*>(gsrc),
      (__attribute__((address_space(3))) void*)(void*)ldsdst,
      16, 0, 0);
}

struct GemmP {
  const unsigned short* Ah; const unsigned short* Al; long sA; int lda;
  const unsigned short* Bh; const unsigned short* Bl; long sB; int ldb;
  float* Cf; unsigned short* Ch; unsigned short* Cl; long sC; int ldc;
  int kspan; int zparts;
  const float* rowv; const float* colv; const float* bq; const float* bk;
  float scale; float tconst;
};

enum { EPI_F32 = 0, EPI_SPLIT = 1, EPI_BF16 = 2, EPI_DOTS = 3, EPI_OUT = 4 };

// NT GEMM: out[i][j] = sum_k A[i][k]*B[j][k]; optional hi/lo split operands (3-pass).
template <int BM, int BN, bool SA, bool SB, int EPI>
__global__ __launch_bounds__(256) void gemm_nt(GemmP g) {
  constexpr int KC = 32;
  constexpr int ASZ = BM * KC, BSZ = BN * KC;
  __shared__ alignas(16) unsigned short lds[(SA ? 2 : 1) * ASZ + (SB ? 2 : 1) * BSZ];
  unsigned short* ldsAh = lds;
  unsigned short* ldsAl = lds + ASZ;
  unsigned short* ldsBh = lds + (SA ? 2 : 1) * ASZ;
  unsigned short* ldsBl = ldsBh + BSZ;

  const int tid = threadIdx.x;
  const int lane = tid & 63, wid = tid >> 6;
  const int wm = wid >> 1, wn = wid & 1;
  constexpr int WM = BM / 2, WN = BN / 2, MF = WM / 16, NF = WN / 16;

  const int bm = blockIdx.x, bn = blockIdx.y, z = blockIdx.z;
  const int b = z / g.zparts, kp = z - b * g.zparts;

  const unsigned short* Ah = g.Ah + (size_t)b * g.sA + (size_t)kp * g.kspan;
  const unsigned short* Al = SA ? (g.Al + (size_t)b * g.sA + (size_t)kp * g.kspan) : nullptr;
  const unsigned short* Bh = g.Bh + (size_t)b * g.sB + (size_t)kp * g.kspan;
  const unsigned short* Bl = SB ? (g.Bl + (size_t)b * g.sB + (size_t)kp * g.kspan) : nullptr;

  f32x4 acc[MF][NF] = {};

  const int kIters = g.kspan / KC;
  for (int kt = 0; kt < kIters; ++kt) {
    const int kb = kt * KC;
#pragma unroll
    for (int r = 0; r < BM / 64; ++r) {
      int idx = tid + r * 256;
      int row = idx >> 2, kc = (idx & 3) << 3;
      size_t goff = (size_t)(bm * BM + row) * g.lda + kb + kc;
      async16(&ldsAh[idx << 3], Ah + goff);
      if constexpr (SA) async16(&ldsAl[idx << 3], Al + goff);
    }
#pragma unroll
    for (int r = 0; r < BN / 64; ++r) {
      int idx = tid + r * 256;
      int row = idx >> 2, kc = (idx & 3) << 3;
      size_t goff = (size_t)(bn * BN + row) * g.ldb + kb + kc;
      async16(&ldsBh[idx << 3], Bh + goff);
      if constexpr (SB) async16(&ldsBl[idx << 3], Bl + goff);
    }
    __syncthreads();

    bf16x8 afh[MF], afl[MF], bfh[NF], bfl[NF];
    const int rsel = lane & 15, ksel = (lane >> 4) << 3;
#pragma unroll
    for (int fm = 0; fm < MF; ++fm) {
      int ro = (wm * WM + fm * 16 + rsel) * KC + ksel;
      afh[fm] = *(const bf16x8*)&ldsAh[ro];
      if constexpr (SA) afl[fm] = *(const bf16x8*)&ldsAl[ro];
    }
#pragma unroll
    for (int fn = 0; fn < NF; ++fn) {
      int ro = (wn * WN + fn * 16 + rsel) * KC + ksel;
      bfh[fn] = *(const bf16x8*)&ldsBh[ro];
      if constexpr (SB) bfl[fn] = *(const bf16x8*)&ldsBl[ro];
    }
#pragma unroll
    for (int fm = 0; fm < MF; ++fm)
#pragma unroll
      for (int fn = 0; fn < NF; ++fn) {
        acc[fm][fn] = __builtin_amdgcn_mfma_f32_16x16x32_bf16(afh[fm], bfh[fn], acc[fm][fn], 0, 0, 0);
        if constexpr (SB) acc[fm][fn] = __builtin_amdgcn_mfma_f32_16x16x32_bf16(afh[fm], bfl[fn], acc[fm][fn], 0, 0, 0);
        if constexpr (SA) acc[fm][fn] = __builtin_amdgcn_mfma_f32_16x16x32_bf16(afl[fm], bfh[fn], acc[fm][fn], 0, 0, 0);
      }
    __syncthreads();
  }

#pragma unroll
  for (int fm = 0; fm < MF; ++fm)
#pragma unroll
    for (int fn = 0; fn < NF; ++fn)
#pragma unroll
      for (int r = 0; r < 4; ++r) {
        int i = bm * BM + wm * WM + fm * 16 + ((lane >> 4) << 2) + r;
        int j = bn * BN + wn * WN + fn * 16 + (lane & 15);
        float v = acc[fm][fn][r];
        size_t co = (size_t)z * g.sC + (size_t)i * g.ldc + j;
        if constexpr (EPI == EPI_F32) {
          g.Cf[co] = v;
        } else if constexpr (EPI == EPI_SPLIT) {
          unsigned short h = f2bf(v);
          g.Ch[co] = h;
          g.Cl[co] = f2bf(v - bf2f(h));
        } else if constexpr (EPI == EPI_BF16) {
          g.Ch[co] = f2bf(v);
        } else if constexpr (EPI == EPI_DOTS) {
          float d = g.scale * (v + g.rowv[b * C_ + i] * g.bk[j] +
                               g.bq[i] * (g.colv[b * C_ + j] + g.tconst * g.bk[j]));
          g.Cf[co] = d;
        } else {  // EPI_OUT
          g.Cf[co] = v + g.rowv[b * C_ + i];
        }
      }
}

// x (B,C,T) fp32 -> Xh,Xl bf16 + row sums s[b,c]
__global__ __launch_bounds__(256) void prep_x(const float* __restrict__ x,
                                              unsigned short* __restrict__ xh,
                                              unsigned short* __restrict__ xl,
                                              float* __restrict__ s) {
  const int row = blockIdx.x;  // b*C + c
  const int tid = threadIdx.x;
  const float* xr = x + (size_t)row * T_;
  unsigned short* hr = xh + (size_t)row * T_;
  unsigned short* lr = xl + (size_t)row * T_;
  float sum = 0.f;
#pragma unroll
  for (int it = 0; it < 4; ++it) {
    int i = (tid + it * 256) * 4;
    float4 v = *(const float4*)&xr[i];
    ushort4 h, l;
    h.x = f2bf(v.x); l.x = f2bf(v.x - bf2f(h.x));
    h.y = f2bf(v.y); l.y = f2bf(v.y - bf2f(h.y));
    h.z = f2bf(v.z); l.z = f2bf(v.z - bf2f(h.z));
    h.w = f2bf(v.w); l.w = f2bf(v.w - bf2f(h.w));
    *(ushort4*)&hr[i] = h;
    *(ushort4*)&lr[i] = l;
    sum += v.x + v.y + v.z + v.w;
  }
  __shared__ float red[4];
  int lane = tid & 63, wid = tid >> 6;
#pragma unroll
  for (int o = 32; o > 0; o >>= 1) sum += __shfl_down(sum, o);
  if (lane == 0) red[wid] = sum;
  __syncthreads();
  if (tid == 0) s[row] = red[0] + red[1] + red[2] + red[3];
}

// weights: Wq,Wk -> hi/lo bf16; Wv -> transposed bf16
__global__ __launch_bounds__(256) void prep_w(const float* __restrict__ Wq, const float* __restrict__ Wk,
                                              const float* __restrict__ Wv,
                                              unsigned short* Wqh, unsigned short* Wql,
                                              unsigned short* Wkh, unsigned short* Wkl,
                                              unsigned short* WvT) {
  int i = blockIdx.x * 256 + threadIdx.x;  // 0..C*C-1
  float q = Wq[i]; unsigned short qh = f2bf(q); Wqh[i] = qh; Wql[i] = f2bf(q - bf2f(qh));
  float k = Wk[i]; unsigned short kh = f2bf(k); Wkh[i] = kh; Wkl[i] = f2bf(k - bf2f(kh));
  float v = Wv[i]; int d = i >> 9, e = i & 511;
  WvT[(e << 9) + d] = f2bf(v);
}

// Xh (B,C,T) -> XhT (B,T,C)
__global__ __launch_bounds__(256) void transpose_xh(const unsigned short* __restrict__ xh,
                                                    unsigned short* __restrict__ xht) {
  __shared__ alignas(16) unsigned short tile[64 * 72];
  const int t0 = blockIdx.x * 64, c0 = blockIdx.y * 64, b = blockIdx.z;
  const unsigned short* in = xh + (size_t)b * C_ * T_;
  unsigned short* out = xht + (size_t)b * C_ * T_;
  const int tid = threadIdx.x;
#pragma unroll
  for (int r = 0; r < 2; ++r) {
    int idx = tid + r * 256;
    int row = idx >> 3, cc = (idx & 7) << 3;
    uint4 v = *(const uint4*)&in[(size_t)(c0 + row) * T_ + t0 + cc];
    *(uint4*)&tile[row * 72 + cc] = v;
  }
  __syncthreads();
#pragma unroll
  for (int r = 0; r < 2; ++r) {
    int idx = tid + r * 256;
    int trow = idx >> 3, cc = (idx & 7) << 3;
    unsigned short vals[8];
#pragma unroll
    for (int j = 0; j < 8; ++j) vals[j] = tile[(cc + j) * 72 + trow];
    *(uint4*)&out[(size_t)(t0 + trow) * C_ + c0 + cc] = *(uint4*)vals;
  }
}

// G split-K partial combine + hi/lo split
__global__ __launch_bounds__(256) void combine_g(const float* __restrict__ gp,
                                                 unsigned short* __restrict__ gh,
                                                 unsigned short* __restrict__ gl) {
  int i = blockIdx.x * 256 + threadIdx.x;  // 0..B*C*C-1
  int b = i >> 18, w = i & 0x3FFFF;
  float v = gp[((size_t)(b * 2) << 18) + w] + gp[((size_t)(b * 2 + 1) << 18) + w];
  unsigned short h = f2bf(v);
  gh[i] = h;
  gl[i] = f2bf(v - bf2f(h));
}

// qs[b,i] = sum_c Wq[i,c] s[b,c];  ks[b,i] = sum_c Wk[i,c] s[b,c]
__global__ __launch_bounds__(256) void qs_ks(const float* __restrict__ Wq, const float* __restrict__ Wk,
                                             const float* __restrict__ s, float* __restrict__ qs,
                                             float* __restrict__ ks) {
  int lane = threadIdx.x & 63, wid = threadIdx.x >> 6;
  int gi = blockIdx.x * 4 + wid;  // 0..B*C-1
  int b = gi >> 9, i = gi & 511;
  const float* sv = s + (b << 9);
  const float* wqr = Wq + (size_t)i * C_;
  const float* wkr = Wk + (size_t)i * C_;
  float aq = 0.f, ak = 0.f;
#pragma unroll
  for (int c = lane; c < C_; c += 64) {
    float sc = sv[c];
    aq += wqr[c] * sc;
    ak += wkr[c] * sc;
  }
#pragma unroll
  for (int o = 32; o > 0; o >>= 1) { aq += __shfl_down(aq, o); ak += __shfl_down(ak, o); }
  if (lane == 0) { qs[gi] = aq; ks[gi] = ak; }
}

// rowwise softmax over 512 logits; attn bf16; ab[b,c] = sum_d attn*bv[d]
__global__ __launch_bounds__(256) void softmax_rows(const float* __restrict__ logits,
                                                    const float* __restrict__ bv,
                                                    unsigned short* __restrict__ attn,
                                                    float* __restrict__ ab) {
  const int row = blockIdx.x;
  const int tid = threadIdx.x, lane = tid & 63, wid = tid >> 6;
  const float* L = logits + (size_t)row * C_;
  float v0 = L[tid], v1 = L[tid + 256];
  __shared__ float red[4];
  float m = fmaxf(v0, v1);
#pragma unroll
  for (int o = 32; o > 0; o >>= 1) m = fmaxf(m, __shfl_down(m, o));
  if (lane == 0) red[wid] = m;
  __syncthreads();
  m = fmaxf(fmaxf(red[0], red[1]), fmaxf(red[2], red[3]));
  __syncthreads();
  float e0 = __expf(v0 - m), e1 = __expf(v1 - m);
  float sum = e0 + e1;
#pragma unroll
  for (int o = 32; o > 0; o >>= 1) sum += __shfl_down(sum, o);
  if (lane == 0) red[wid] = sum;
  __syncthreads();
  sum = red[0] + red[1] + red[2] + red[3];
  float inv = 1.f / sum;
  float a0 = e0 * inv, a1 = e1 * inv;
  unsigned short* ar = attn + (size_t)row * C_;
  ar[tid] = f2bf(a0);
  ar[tid + 256] = f2bf(a1);
  float abv = a0 * bv[tid] + a1 * bv[tid + 256];
  __syncthreads();
#pragma unroll
  for (int o = 32; o > 0; o >>= 1) abv += __shfl_down(abv, o);
  if (lane == 0) red[wid] = abv;
  __syncthreads();
  if (tid == 0) ab[row] = red[0] + red[1] + red[2] + red[3];
}

extern "C" void kernel_launch(void* const* d_in, const int* in_sizes, int n_in,
                              void* d_out, int out_size, void* d_ws, size_t ws_size,
                              hipStream_t stream) {
  const float* x  = (const float*)d_in[0];
  const float* Wq = (const float*)d_in[1];
  const float* bq = (const float*)d_in[2];
  const float* Wk = (const float*)d_in[3];
  const float* bk = (const float*)d_in[4];
  const float* Wv = (const float*)d_in[5];
  const float* bv = (const float*)d_in[6];
  float* out = (float*)d_out;

  char* ws = (char*)d_ws;
  size_t off = 0;
  auto alloc = [&](size_t bytes) {
    char* p = ws + off;
    off += (bytes + 255) & ~(size_t)255;
    return p;
  };
  const size_t XSZ = (size_t)B_ * C_ * T_;   // elements
  const size_t GSZ = (size_t)B_ * C_ * C_;

  unsigned short* Xh = (unsigned short*)alloc(XSZ * 2);
  unsigned short* Xl = (unsigned short*)alloc(XSZ * 2);   // aliased later by XhT
  unsigned short* XhT = Xl;                                // transpose runs after G GEMM
  float* Gpart = (float*)alloc((size_t)2 * GSZ * 4);       // aliased later by Ph/Pl
  unsigned short* Ph = (unsigned short*)Gpart;
  unsigned short* Pl = (unsigned short*)Gpart + GSZ;
  unsigned short* Gh = (unsigned short*)alloc(GSZ * 2);
  unsigned short* Gl = (unsigned short*)alloc(GSZ * 2);
  float* Logits = (float*)alloc(GSZ * 4);
  unsigned short* Attn = (unsigned short*)alloc(GSZ * 2);
  unsigned short* Mh = (unsigned short*)alloc(GSZ * 2);
  unsigned short* Wqh = (unsigned short*)alloc((size_t)C_ * C_ * 2);
  unsigned short* Wql = (unsigned short*)alloc((size_t)C_ * C_ * 2);
  unsigned short* Wkh = (unsigned short*)alloc((size_t)C_ * C_ * 2);
  unsigned short* Wkl = (unsigned short*)alloc((size_t)C_ * C_ * 2);
  unsigned short* WvT = (unsigned short*)alloc((size_t)C_ * C_ * 2);
  float* S  = (float*)alloc((size_t)B_ * C_ * 4);
  float* Qs = (float*)alloc((size_t)B_ * C_ * 4);
  float* Ks = (float*)alloc((size_t)B_ * C_ * 4);
  float* Ab = (float*)alloc((size_t)B_ * C_ * 4);

  prep_x<<<B_ * C_, 256, 0, stream>>>(x, Xh, Xl, S);
  prep_w<<<C_ * C_ / 256, 256, 0, stream>>>(Wq, Wk, Wv, Wqh, Wql, Wkh, Wkl, WvT);
  qs_ks<<<B_ * C_ / 4, 256, 0, stream>>>(Wq, Wk, S, Qs, Ks);

  {  // G = X X^T per batch, split-K=2, fp32 partials
    GemmP p = {};
    p.Ah = Xh; p.Al = Xl; p.sA = (long)C_ * T_; p.lda = T_;
    p.Bh = Xh; p.Bl = Xl; p.sB = (long)C_ * T_; p.ldb = T_;
    p.Cf = Gpart; p.sC = (long)C_ * C_; p.ldc = C_;
    p.kspan = T_ / 2; p.zparts = 2;
    gemm_nt<128, 128, true, true, EPI_F32><<<dim3(4, 4, 16), 256, 0, stream>>>(p);
  }
  combine_g<<<(int)(GSZ / 256), 256, 0, stream>>>(Gpart, Gh, Gl);
  transpose_xh<<<dim3(T_ / 64, C_ / 64, B_), 256, 0, stream>>>(Xh, XhT);  // overwrites Xl

  {  // P = Wq G  (split output)
    GemmP p = {};
    p.Ah = Wqh; p.Al = Wql; p.sA = 0; p.lda = C_;
    p.Bh = Gh; p.Bl = Gl; p.sB = (long)C_ * C_; p.ldb = C_;
    p.Ch = Ph; p.Cl = Pl; p.sC = (long)C_ * C_; p.ldc = C_;
    p.kspan = C_; p.zparts = 1;
    gemm_nt<64, 64, true, true, EPI_SPLIT><<<dim3(8, 8, 8), 256, 0, stream>>>(p);
  }
  {  // logits = SCALE*(P Wk^T + qs bk^T + bq ks^T + T bq bk^T)
    GemmP p = {};
    p.Ah = Ph; p.Al = Pl; p.sA = (long)C_ * C_; p.lda = C_;
    p.Bh = Wkh; p.Bl = Wkl; p.sB = 0; p.ldb = C_;
    p.Cf = Logits; p.sC = (long)C_ * C_; p.ldc = C_;
    p.kspan = C_; p.zparts = 1;
    p.rowv = Qs; p.colv = Ks; p.bq = bq; p.bk = bk;
    p.scale = 0.125f; p.tconst = (float)T_;
    gemm_nt<64, 64, true, true, EPI_DOTS><<<dim3(8, 8, 8), 256, 0, stream>>>(p);
  }
  softmax_rows<<<B_ * C_, 256, 0, stream>>>(Logits, bv, Attn, Ab);
  {  // M = attn Wv  (NT with WvT)
    GemmP p = {};
    p.Ah = Attn; p.sA = (long)C_ * C_; p.lda = C_;
    p.Bh = WvT; p.sB = 0; p.ldb = C_;
    p.Ch = Mh; p.sC = (long)C_ * C_; p.ldc = C_;
    p.kspan = C_; p.zparts = 1;
    gemm_nt<64, 64, false, false, EPI_BF16><<<dim3(8, 8, 8), 256, 0, stream>>>(p);
  }
  {  // out = M X + ab  (NT with XhT)
    GemmP p = {};
    p.Ah = Mh; p.sA = (long)C_ * C_; p.lda = C_;
    p.Bh = XhT; p.sB = (long)C_ * T_; p.ldb = C_;
    p.Cf = out; p.sC = (long)C_ * T_; p.ldc = T_;
    p.kspan = C_; p.zparts = 1;
    p.rowv = Ab;
    gemm_nt<128, 128, false, false, EPI_OUT><<<dim3(C_ / 128, T_ / 128, B_), 256, 0, stream>>>(p);
  }
  (void)in_sizes; (void)n_in; (void)out_size; (void)ws_size;
}

// Round 2
// 281.088 us; speedup vs baseline: 1.1949x; 1.1949x over previous
//
#include <hip/hip_runtime.h>

#define B_ 8
#define C_ 512
#define T_ 4096

typedef __attribute__((ext_vector_type(8))) __bf16 bf16x8;
typedef __attribute__((ext_vector_type(8))) _Float16 f16x8;
typedef __attribute__((ext_vector_type(8))) unsigned short u16x8;
typedef __attribute__((ext_vector_type(4))) float f32x4;

__device__ __forceinline__ unsigned short f2bf(float f) {
  unsigned int u = __float_as_uint(f);
  u += 0x7fffu + ((u >> 16) & 1u);   // RNE
  return (unsigned short)(u >> 16);
}
__device__ __forceinline__ float bf2f(unsigned short h) {
  return __uint_as_float(((unsigned int)h) << 16);
}
__device__ __forceinline__ unsigned short f2h(float f) {
  return __builtin_bit_cast(unsigned short, (_Float16)f);
}

__device__ __forceinline__ void async16(unsigned short* ldsdst, const unsigned short* gsrc) {
  __builtin_amdgcn_global_load_lds(
      (__attribute__((address_space(1))) void*)(void*)const_cast<unsigned short*>(gsrc),
      (__attribute__((address_space(3))) void*)(void*)ldsdst,
      16, 0, 0);
}

template <bool F16>
__device__ __forceinline__ f32x4 mfma16(u16x8 a, u16x8 b, f32x4 c) {
  if constexpr (F16)
    return __builtin_amdgcn_mfma_f32_16x16x32_f16(
        __builtin_bit_cast(f16x8, a), __builtin_bit_cast(f16x8, b), c, 0, 0, 0);
  else
    return __builtin_amdgcn_mfma_f32_16x16x32_bf16(
        __builtin_bit_cast(bf16x8, a), __builtin_bit_cast(bf16x8, b), c, 0, 0, 0);
}

struct GemmP {
  const unsigned short* Ah; const unsigned short* Al; long sA; int lda;
  const unsigned short* Bh; const unsigned short* Bl; long sB; int ldb;
  float* Cf; unsigned short* Ch; unsigned short* Cl; long sC; int ldc;
  int kspan; int zparts;
  const float* rowv; const float* colv; const float* bq; const float* bk;
  float scale; float tconst;
};

enum { EPI_F32 = 0, EPI_SPLIT = 1, EPI_F16 = 2, EPI_DOTS = 3, EPI_OUT = 4 };

// NT GEMM: out[i][j] = sum_k A[i][k]*B[j][k]; optional hi/lo split operands (3-pass).
template <int BM, int BN, bool SA, bool SB, int EPI, bool F16>
__global__ __launch_bounds__(256) void gemm_nt(GemmP g) {
  constexpr int KC = 32;
  constexpr int ASZ = BM * KC, BSZ = BN * KC;
  __shared__ alignas(16) unsigned short lds[(SA ? 2 : 1) * ASZ + (SB ? 2 : 1) * BSZ];
  unsigned short* ldsAh = lds;
  unsigned short* ldsAl = lds + ASZ;
  unsigned short* ldsBh = lds + (SA ? 2 : 1) * ASZ;
  unsigned short* ldsBl = ldsBh + BSZ;

  const int tid = threadIdx.x;
  const int lane = tid & 63, wid = tid >> 6;
  const int wm = wid >> 1, wn = wid & 1;
  constexpr int WM = BM / 2, WN = BN / 2, MF = WM / 16, NF = WN / 16;

  const int bm = blockIdx.x, bn = blockIdx.y, z = blockIdx.z;
  const int b = z / g.zparts, kp = z - b * g.zparts;

  const unsigned short* Ah = g.Ah + (size_t)b * g.sA + (size_t)kp * g.kspan;
  const unsigned short* Al = SA ? (g.Al + (size_t)b * g.sA + (size_t)kp * g.kspan) : nullptr;
  const unsigned short* Bh = g.Bh + (size_t)b * g.sB + (size_t)kp * g.kspan;
  const unsigned short* Bl = SB ? (g.Bl + (size_t)b * g.sB + (size_t)kp * g.kspan) : nullptr;

  f32x4 acc[MF][NF] = {};

  const int kIters = g.kspan / KC;
  for (int kt = 0; kt < kIters; ++kt) {
    const int kb = kt * KC;
#pragma unroll
    for (int r = 0; r < BM / 64; ++r) {
      int idx = tid + r * 256;
      int row = idx >> 2, kc = (idx & 3) << 3;
      size_t goff = (size_t)(bm * BM + row) * g.lda + kb + kc;
      async16(&ldsAh[idx << 3], Ah + goff);
      if constexpr (SA) async16(&ldsAl[idx << 3], Al + goff);
    }
#pragma unroll
    for (int r = 0; r < BN / 64; ++r) {
      int idx = tid + r * 256;
      int row = idx >> 2, kc = (idx & 3) << 3;
      size_t goff = (size_t)(bn * BN + row) * g.ldb + kb + kc;
      async16(&ldsBh[idx << 3], Bh + goff);
      if constexpr (SB) async16(&ldsBl[idx << 3], Bl + goff);
    }
    __syncthreads();

    u16x8 afh[MF], afl[MF], bfh[NF], bfl[NF];
    const int rsel = lane & 15, ksel = (lane >> 4) << 3;
#pragma unroll
    for (int fm = 0; fm < MF; ++fm) {
      int ro = (wm * WM + fm * 16 + rsel) * KC + ksel;
      afh[fm] = *(const u16x8*)&ldsAh[ro];
      if constexpr (SA) afl[fm] = *(const u16x8*)&ldsAl[ro];
    }
#pragma unroll
    for (int fn = 0; fn < NF; ++fn) {
      int ro = (wn * WN + fn * 16 + rsel) * KC + ksel;
      bfh[fn] = *(const u16x8*)&ldsBh[ro];
      if constexpr (SB) bfl[fn] = *(const u16x8*)&ldsBl[ro];
    }
#pragma unroll
    for (int fm = 0; fm < MF; ++fm)
#pragma unroll
      for (int fn = 0; fn < NF; ++fn) {
        acc[fm][fn] = mfma16<F16>(afh[fm], bfh[fn], acc[fm][fn]);
        if constexpr (SB) acc[fm][fn] = mfma16<F16>(afh[fm], bfl[fn], acc[fm][fn]);
        if constexpr (SA) acc[fm][fn] = mfma16<F16>(afl[fm], bfh[fn], acc[fm][fn]);
      }
    __syncthreads();
  }

#pragma unroll
  for (int fm = 0; fm < MF; ++fm)
#pragma unroll
    for (int fn = 0; fn < NF; ++fn)
#pragma unroll
      for (int r = 0; r < 4; ++r) {
        int i = bm * BM + wm * WM + fm * 16 + ((lane >> 4) << 2) + r;
        int j = bn * BN + wn * WN + fn * 16 + (lane & 15);
        float v = acc[fm][fn][r];
        size_t co = (size_t)z * g.sC + (size_t)i * g.ldc + j;
        if constexpr (EPI == EPI_F32) {
          g.Cf[co] = v;
        } else if constexpr (EPI == EPI_SPLIT) {
          unsigned short h = f2bf(v);
          g.Ch[co] = h;
          g.Cl[co] = f2bf(v - bf2f(h));
        } else if constexpr (EPI == EPI_F16) {
          g.Ch[co] = f2h(v);
        } else if constexpr (EPI == EPI_DOTS) {
          float d = g.scale * (v + g.rowv[b * C_ + i] * g.bk[j] +
                               g.bq[i] * (g.colv[b * C_ + j] + g.tconst * g.bk[j]));
          g.Cf[co] = d;
        } else {  // EPI_OUT
          g.Cf[co] = v + g.rowv[b * C_ + i];
        }
      }
}

// Fused prep: x-tiles (convert fp32->fp16, write Xh + XhT via LDS, row sums via
// atomics) plus weight blocks (Wq/Wk -> bf16 hi/lo, Wv -> transposed fp16).
#define NXB (64 * 8 * 8)
#define PAD 66
__global__ __launch_bounds__(256) void prep_fused(
    const float* __restrict__ x, const float* __restrict__ Wq,
    const float* __restrict__ Wk, const float* __restrict__ Wv,
    unsigned short* __restrict__ Xh, unsigned short* __restrict__ XhT,
    float* __restrict__ S, unsigned short* Wqh, unsigned short* Wql,
    unsigned short* Wkh, unsigned short* Wkl, unsigned short* WvT) {
  __shared__ unsigned short tile[64 * PAD];
  const int tid = threadIdx.x;
  if (blockIdx.x < NXB) {
    const int tl = blockIdx.x;
    const int t0 = (tl & 63) << 6, c0 = ((tl >> 6) & 7) << 6, b = tl >> 9;
    const float* xin = x + ((size_t)(b * C_ + c0)) * T_ + t0;
    unsigned short* xo = Xh + ((size_t)(b * C_ + c0)) * T_ + t0;
#pragma unroll
    for (int r = 0; r < 4; ++r) {
      int p = tid + r * 256;
      int row = p >> 4, c4 = (p & 15) << 2;
      float4 v = *(const float4*)&xin[(size_t)row * T_ + c4];
      unsigned short h0 = f2h(v.x), h1 = f2h(v.y), h2 = f2h(v.z), h3 = f2h(v.w);
      ushort4 hv; hv.x = h0; hv.y = h1; hv.z = h2; hv.w = h3;
      *(ushort4*)&xo[(size_t)row * T_ + c4] = hv;
      unsigned int lo = (unsigned int)h0 | ((unsigned int)h1 << 16);
      unsigned int hi = (unsigned int)h2 | ((unsigned int)h3 << 16);
      ((unsigned int*)&tile[row * PAD + c4])[0] = lo;
      ((unsigned int*)&tile[row * PAD + c4])[1] = hi;
      float s = v.x + v.y + v.z + v.w;
#pragma unroll
      for (int o = 1; o < 16; o <<= 1) s += __shfl_xor(s, o);
      if ((tid & 15) == 0) atomicAdd(&S[b * C_ + c0 + row], s);
    }
    __syncthreads();
#pragma unroll
    for (int r = 0; r < 2; ++r) {
      int idx = tid + r * 256;
      int trow = idx >> 3, cc = (idx & 7) << 3;
      unsigned short vals[8];
#pragma unroll
      for (int j = 0; j < 8; ++j) vals[j] = tile[(cc + j) * PAD + trow];
      *(uint4*)&XhT[((size_t)b * T_ + t0 + trow) * C_ + c0 + cc] = *(uint4*)vals;
    }
  } else {
    int i = (blockIdx.x - NXB) * 256 + tid;  // 0..C*C-1
    float q = Wq[i]; unsigned short qh = f2bf(q); Wqh[i] = qh; Wql[i] = f2bf(q - bf2f(qh));
    float k = Wk[i]; unsigned short kh = f2bf(k); Wkh[i] = kh; Wkl[i] = f2bf(k - bf2f(kh));
    float v = Wv[i]; int d = i >> 9, e = i & 511;
    WvT[(e << 9) + d] = f2h(v);
  }
}

// G split-K (4 parts) combine + bf16 hi/lo split
__global__ __launch_bounds__(256) void combine_g(const float* __restrict__ gp,
                                                 unsigned short* __restrict__ gh,
                                                 unsigned short* __restrict__ gl) {
  int i = blockIdx.x * 256 + threadIdx.x;  // 0..B*C*C-1
  int b = i >> 18, w = i & 0x3FFFF;
  const float* base = gp + ((size_t)(b * 4) << 18);
  float v = base[w] + base[(1 << 18) + w] + base[(2 << 18) + w] + base[(3 << 18) + w];
  unsigned short h = f2bf(v);
  gh[i] = h;
  gl[i] = f2bf(v - bf2f(h));
}

// qs[b,i] = sum_c Wq[i,c] s[b,c];  ks[b,i] = sum_c Wk[i,c] s[b,c]
__global__ __launch_bounds__(256) void qs_ks(const float* __restrict__ Wq, const float* __restrict__ Wk,
                                             const float* __restrict__ s, float* __restrict__ qs,
                                             float* __restrict__ ks) {
  int lane = threadIdx.x & 63, wid = threadIdx.x >> 6;
  int gi = blockIdx.x * 4 + wid;  // 0..B*C-1
  int b = gi >> 9, i = gi & 511;
  const float* sv = s + (b << 9);
  const float* wqr = Wq + (size_t)i * C_;
  const float* wkr = Wk + (size_t)i * C_;
  float aq = 0.f, ak = 0.f;
#pragma unroll
  for (int c = lane; c < C_; c += 64) {
    float sc = sv[c];
    aq += wqr[c] * sc;
    ak += wkr[c] * sc;
  }
#pragma unroll
  for (int o = 32; o > 0; o >>= 1) { aq += __shfl_down(aq, o); ak += __shfl_down(ak, o); }
  if (lane == 0) { qs[gi] = aq; ks[gi] = ak; }
}

// rowwise softmax over 512 logits; attn fp16; ab[b,c] = sum_d attn*bv[d]
__global__ __launch_bounds__(256) void softmax_rows(const float* __restrict__ logits,
                                                    const float* __restrict__ bv,
                                                    unsigned short* __restrict__ attn,
                                                    float* __restrict__ ab) {
  const int row = blockIdx.x;
  const int tid = threadIdx.x, lane = tid & 63, wid = tid >> 6;
  const float* L = logits + (size_t)row * C_;
  float v0 = L[tid], v1 = L[tid + 256];
  __shared__ float red[4];
  float m = fmaxf(v0, v1);
#pragma unroll
  for (int o = 32; o > 0; o >>= 1) m = fmaxf(m, __shfl_down(m, o));
  if (lane == 0) red[wid] = m;
  __syncthreads();
  m = fmaxf(fmaxf(red[0], red[1]), fmaxf(red[2], red[3]));
  __syncthreads();
  float e0 = __expf(v0 - m), e1 = __expf(v1 - m);
  float sum = e0 + e1;
#pragma unroll
  for (int o = 32; o > 0; o >>= 1) sum += __shfl_down(sum, o);
  if (lane == 0) red[wid] = sum;
  __syncthreads();
  sum = red[0] + red[1] + red[2] + red[3];
  float inv = 1.f / sum;
  float a0 = e0 * inv, a1 = e1 * inv;
  unsigned short* ar = attn + (size_t)row * C_;
  ar[tid] = f2h(a0);
  ar[tid + 256] = f2h(a1);
  float abv = a0 * bv[tid] + a1 * bv[tid + 256];
  __syncthreads();
#pragma unroll
  for (int o = 32; o > 0; o >>= 1) abv += __shfl_down(abv, o);
  if (lane == 0) red[wid] = abv;
  __syncthreads();
  if (tid == 0) ab[row] = red[0] + red[1] + red[2] + red[3];
}

extern "C" void kernel_launch(void* const* d_in, const int* in_sizes, int n_in,
                              void* d_out, int out_size, void* d_ws, size_t ws_size,
                              hipStream_t stream) {
  const float* x  = (const float*)d_in[0];
  const float* Wq = (const float*)d_in[1];
  const float* bq = (const float*)d_in[2];
  const float* Wk = (const float*)d_in[3];
  const float* bk = (const float*)d_in[4];
  const float* Wv = (const float*)d_in[5];
  const float* bv = (const float*)d_in[6];
  float* out = (float*)d_out;

  char* ws = (char*)d_ws;
  size_t off = 0;
  auto alloc = [&](size_t bytes) {
    char* p = ws + off;
    off += (bytes + 255) & ~(size_t)255;
    return p;
  };
  const size_t XSZ = (size_t)B_ * C_ * T_;   // elements
  const size_t GSZ = (size_t)B_ * C_ * C_;

  unsigned short* Xh  = (unsigned short*)alloc(XSZ * 2);
  unsigned short* XhT = (unsigned short*)alloc(XSZ * 2);
  float* Gpart = (float*)alloc((size_t)4 * GSZ * 4);       // 32 MB; aliased after combine:
  unsigned short* Ph   = (unsigned short*)Gpart;            //  0.. 4 MB
  unsigned short* Pl   = (unsigned short*)Gpart + GSZ;      //  4.. 8 MB
  float*          Logits = (float*)((char*)Gpart + GSZ * 4);          //  8..16 MB
  unsigned short* Attn = (unsigned short*)((char*)Gpart + GSZ * 8);   // 16..20 MB
  unsigned short* Mh   = (unsigned short*)((char*)Gpart + GSZ * 10);  // 20..24 MB
  unsigned short* Gh = (unsigned short*)alloc(GSZ * 2);
  unsigned short* Gl = (unsigned short*)alloc(GSZ * 2);
  unsigned short* Wqh = (unsigned short*)alloc((size_t)C_ * C_ * 2);
  unsigned short* Wql = (unsigned short*)alloc((size_t)C_ * C_ * 2);
  unsigned short* Wkh = (unsigned short*)alloc((size_t)C_ * C_ * 2);
  unsigned short* Wkl = (unsigned short*)alloc((size_t)C_ * C_ * 2);
  unsigned short* WvT = (unsigned short*)alloc((size_t)C_ * C_ * 2);
  float* S  = (float*)alloc((size_t)B_ * C_ * 4);
  float* Qs = (float*)alloc((size_t)B_ * C_ * 4);
  float* Ks = (float*)alloc((size_t)B_ * C_ * 4);
  float* Ab = (float*)alloc((size_t)B_ * C_ * 4);

  hipMemsetAsync(S, 0, (size_t)B_ * C_ * 4, stream);
  prep_fused<<<NXB + C_ * C_ / 256, 256, 0, stream>>>(x, Wq, Wk, Wv, Xh, XhT, S,
                                                      Wqh, Wql, Wkh, Wkl, WvT);
  qs_ks<<<B_ * C_ / 4, 256, 0, stream>>>(Wq, Wk, S, Qs, Ks);

  {  // G = X X^T per batch, fp16 single-pass, split-K=4, fp32 partials
    GemmP p = {};
    p.Ah = Xh; p.sA = (long)C_ * T_; p.lda = T_;
    p.Bh = Xh; p.sB = (long)C_ * T_; p.ldb = T_;
    p.Cf = Gpart; p.sC = (long)C_ * C_; p.ldc = C_;
    p.kspan = T_ / 4; p.zparts = 4;
    gemm_nt<128, 128, false, false, EPI_F32, true><<<dim3(4, 4, 32), 256, 0, stream>>>(p);
  }
  combine_g<<<(int)(GSZ / 256), 256, 0, stream>>>(Gpart, Gh, Gl);

  {  // P = Wq G  (bf16 hi/lo 3-pass, split output)
    GemmP p = {};
    p.Ah = Wqh; p.Al = Wql; p.sA = 0; p.lda = C_;
    p.Bh = Gh; p.Bl = Gl; p.sB = (long)C_ * C_; p.ldb = C_;
    p.Ch = Ph; p.Cl = Pl; p.sC = (long)C_ * C_; p.ldc = C_;
    p.kspan = C_; p.zparts = 1;
    gemm_nt<64, 64, true, true, EPI_SPLIT, false><<<dim3(8, 8, 8), 256, 0, stream>>>(p);
  }
  {  // logits = SCALE*(P Wk^T + qs bk^T + bq ks^T + T bq bk^T)
    GemmP p = {};
    p.Ah = Ph; p.Al = Pl; p.sA = (long)C_ * C_; p.lda = C_;
    p.Bh = Wkh; p.Bl = Wkl; p.sB = 0; p.ldb = C_;
    p.Cf = Logits; p.sC = (long)C_ * C_; p.ldc = C_;
    p.kspan = C_; p.zparts = 1;
    p.rowv = Qs; p.colv = Ks; p.bq = bq; p.bk = bk;
    p.scale = 0.125f; p.tconst = (float)T_;
    gemm_nt<64, 64, true, true, EPI_DOTS, false><<<dim3(8, 8, 8), 256, 0, stream>>>(p);
  }
  softmax_rows<<<B_ * C_, 256, 0, stream>>>(Logits, bv, Attn, Ab);
  {  // M = attn Wv  (fp16 single-pass, NT with WvT)
    GemmP p = {};
    p.Ah = Attn; p.sA = (long)C_ * C_; p.lda = C_;
    p.Bh = WvT; p.sB = 0; p.ldb = C_;
    p.Ch = Mh; p.sC = (long)C_ * C_; p.ldc = C_;
    p.kspan = C_; p.zparts = 1;
    gemm_nt<64, 64, false, false, EPI_F16, true><<<dim3(8, 8, 8), 256, 0, stream>>>(p);
  }
  {  // out = M X + ab  (fp16 single-pass, NT with XhT)
    GemmP p = {};
    p.Ah = Mh; p.sA = (long)C_ * C_; p.lda = C_;
    p.Bh = XhT; p.sB = (long)C_ * T_; p.ldb = C_;
    p.Cf = out; p.sC = (long)C_ * T_; p.ldc = T_;
    p.kspan = C_; p.zparts = 1;
    p.rowv = Ab;
    gemm_nt<128, 128, false, false, EPI_OUT, true><<<dim3(C_ / 128, T_ / 128, B_), 256, 0, stream>>>(p);
  }
  (void)in_sizes; (void)n_in; (void)out_size; (void)ws_size;
}

// Round 3
// 279.147 us; speedup vs baseline: 1.2032x; 1.0070x over previous
//
#include <hip/hip_runtime.h>

#define B_ 8
#define C_ 512
#define T_ 4096

typedef __attribute__((ext_vector_type(8))) __bf16 bf16x8;
typedef __attribute__((ext_vector_type(8))) _Float16 f16x8;
typedef __attribute__((ext_vector_type(8))) unsigned short u16x8;
typedef __attribute__((ext_vector_type(4))) float f32x4;

__device__ __forceinline__ unsigned short f2bf(float f) {
  unsigned int u = __float_as_uint(f);
  u += 0x7fffu + ((u >> 16) & 1u);   // RNE
  return (unsigned short)(u >> 16);
}
__device__ __forceinline__ float bf2f(unsigned short h) {
  return __uint_as_float(((unsigned int)h) << 16);
}
__device__ __forceinline__ unsigned short f2h(float f) {
  return __builtin_bit_cast(unsigned short, (_Float16)f);
}

__device__ __forceinline__ void async16(unsigned short* ldsdst, const unsigned short* gsrc) {
  __builtin_amdgcn_global_load_lds(
      (__attribute__((address_space(1))) void*)(void*)const_cast<unsigned short*>(gsrc),
      (__attribute__((address_space(3))) void*)(void*)ldsdst,
      16, 0, 0);
}

template <bool F16>
__device__ __forceinline__ f32x4 mfma16(u16x8 a, u16x8 b, f32x4 c) {
  if constexpr (F16)
    return __builtin_amdgcn_mfma_f32_16x16x32_f16(
        __builtin_bit_cast(f16x8, a), __builtin_bit_cast(f16x8, b), c, 0, 0, 0);
  else
    return __builtin_amdgcn_mfma_f32_16x16x32_bf16(
        __builtin_bit_cast(bf16x8, a), __builtin_bit_cast(bf16x8, b), c, 0, 0, 0);
}

struct GemmP {
  const unsigned short* Ah; const unsigned short* Al; long sA; int lda;
  const unsigned short* Bh; const unsigned short* Bl; long sB; int ldb;
  float* Cf; long sC; int ldc;
  int kspan; int zparts;
  const float* rowv;   // EPI_OUT row-wise add
};

enum { EPI_F32 = 0, EPI_OUT = 1 };

// NT GEMM: C[i][j] = sum_k A[i][k]*B[j][k]; optional hi/lo split (3-pass).
// f32 output always staged through LDS in 32-row chunks -> dwordx4 stores.
template <int BM, int BN, int WM, int WN, int KC, bool SA, bool SB, int EPI, bool F16>
__global__ __launch_bounds__((BM / WM) * (BN / WN) * 64) void gemm_nt(GemmP g) {
  constexpr int NWAVE = (BM / WM) * (BN / WN);
  constexpr int NT = NWAVE * 64;
  constexpr int ASZ = BM * KC, BSZ = BN * KC;
  constexpr int STAGE = (SA ? 2 : 1) * ASZ + (SB ? 2 : 1) * BSZ;  // shorts
  constexpr int EPAD = BN + 4;
  constexpr int EPIB = 32 * EPAD * 4;                              // bytes
  constexpr int LDSB = (STAGE * 2 > EPIB) ? STAGE * 2 : EPIB;
  __shared__ alignas(16) char ldsraw[LDSB];
  unsigned short* lds = (unsigned short*)ldsraw;
  unsigned short* ldsAh = lds;
  unsigned short* ldsAl = lds + ASZ;
  unsigned short* ldsBh = lds + (SA ? 2 : 1) * ASZ;
  unsigned short* ldsBl = ldsBh + BSZ;

  const int tid = threadIdx.x;
  const int lane = tid & 63, wid = tid >> 6;
  constexpr int WNB = BN / WN;
  const int wm = wid / WNB, wn = wid % WNB;
  constexpr int MF = WM / 16, NF = WN / 16;
  constexpr int KCH = KC / 8;  // 16B chunks per row

  const int bm = blockIdx.x, bn = blockIdx.y, z = blockIdx.z;
  const int b = z / g.zparts, kp = z - b * g.zparts;

  const unsigned short* Ah = g.Ah + (size_t)b * g.sA + (size_t)kp * g.kspan;
  const unsigned short* Al = SA ? (g.Al + (size_t)b * g.sA + (size_t)kp * g.kspan) : nullptr;
  const unsigned short* Bh = g.Bh + (size_t)b * g.sB + (size_t)kp * g.kspan;
  const unsigned short* Bl = SB ? (g.Bl + (size_t)b * g.sB + (size_t)kp * g.kspan) : nullptr;

  f32x4 acc[MF][NF] = {};

  const int kIters = g.kspan / KC;
  for (int kt = 0; kt < kIters; ++kt) {
    const int kb = kt * KC;
#pragma unroll
    for (int r = 0; r < ASZ / (8 * NT); ++r) {
      int idx = tid + r * NT;
      int row = idx / KCH, kc = (idx % KCH) << 3;
      size_t goff = (size_t)(bm * BM + row) * g.lda + kb + kc;
      async16(&ldsAh[idx << 3], Ah + goff);
      if constexpr (SA) async16(&ldsAl[idx << 3], Al + goff);
    }
#pragma unroll
    for (int r = 0; r < BSZ / (8 * NT); ++r) {
      int idx = tid + r * NT;
      int row = idx / KCH, kc = (idx % KCH) << 3;
      size_t goff = (size_t)(bn * BN + row) * g.ldb + kb + kc;
      async16(&ldsBh[idx << 3], Bh + goff);
      if constexpr (SB) async16(&ldsBl[idx << 3], Bl + goff);
    }
    __syncthreads();

    const int rsel = lane & 15, ksel = (lane >> 4) << 3;
#pragma unroll
    for (int ks = 0; ks < KC; ks += 32) {
      u16x8 afh[MF], afl[MF], bfh[NF], bfl[NF];
#pragma unroll
      for (int fm = 0; fm < MF; ++fm) {
        int ro = (wm * WM + fm * 16 + rsel) * KC + ks + ksel;
        afh[fm] = *(const u16x8*)&ldsAh[ro];
        if constexpr (SA) afl[fm] = *(const u16x8*)&ldsAl[ro];
      }
#pragma unroll
      for (int fn = 0; fn < NF; ++fn) {
        int ro = (wn * WN + fn * 16 + rsel) * KC + ks + ksel;
        bfh[fn] = *(const u16x8*)&ldsBh[ro];
        if constexpr (SB) bfl[fn] = *(const u16x8*)&ldsBl[ro];
      }
#pragma unroll
      for (int fm = 0; fm < MF; ++fm)
#pragma unroll
        for (int fn = 0; fn < NF; ++fn) {
          acc[fm][fn] = mfma16<F16>(afh[fm], bfh[fn], acc[fm][fn]);
          if constexpr (SB) acc[fm][fn] = mfma16<F16>(afh[fm], bfl[fn], acc[fm][fn]);
          if constexpr (SA) acc[fm][fn] = mfma16<F16>(afl[fm], bfh[fn], acc[fm][fn]);
        }
    }
    __syncthreads();
  }

  // Chunked LDS epilogue: 32 rows x BN f32 per chunk, coalesced dwordx4 stores.
  float* eb = (float*)ldsraw;
#pragma unroll
  for (int ck = 0; ck < BM / 32; ++ck) {
    if (wm == (ck * 32) / WM) {
      const int fm0 = ((ck * 32) % WM) / 16;
#pragma unroll
      for (int fi = 0; fi < 2; ++fi) {
        int fm = fm0 + fi;
#pragma unroll
        for (int fn = 0; fn < NF; ++fn)
#pragma unroll
          for (int r = 0; r < 4; ++r) {
            int lrow = fi * 16 + ((lane >> 4) << 2) + r;
            int col = wn * WN + fn * 16 + (lane & 15);
            eb[lrow * EPAD + col] = acc[fm][fn][r];
          }
      }
    }
    __syncthreads();
#pragma unroll
    for (int it = 0; it < (32 * BN / 4) / NT; ++it) {
      int idx = it * NT + tid;
      int row = idx / (BN / 4), c4 = (idx % (BN / 4)) * 4;
      f32x4 v = *(f32x4*)&eb[row * EPAD + c4];
      int grow = bm * BM + ck * 32 + row;
      if constexpr (EPI == EPI_OUT) v = v + g.rowv[b * C_ + grow];
      *(f32x4*)&g.Cf[(size_t)z * g.sC + (size_t)grow * g.ldc + bn * BN + c4] = v;
    }
    __syncthreads();
  }
}

// Fused prep: x tiles (fp32->fp16 Xh + XhT via LDS, row sums) + weight blocks.
#define NXB (64 * 8 * 8)
#define PAD 66
__global__ __launch_bounds__(256) void prep_fused(
    const float* __restrict__ x, const float* __restrict__ Wq,
    const float* __restrict__ Wk, const float* __restrict__ Wv,
    unsigned short* __restrict__ Xh, unsigned short* __restrict__ XhT,
    float* __restrict__ S, unsigned short* Wqh, unsigned short* Wql,
    unsigned short* Wkh, unsigned short* Wkl, unsigned short* WvT) {
  __shared__ unsigned short tile[64 * PAD];
  const int tid = threadIdx.x;
  if (blockIdx.x < NXB) {
    const int tl = blockIdx.x;
    const int t0 = (tl & 63) << 6, c0 = ((tl >> 6) & 7) << 6, b = tl >> 9;
    const float* xin = x + ((size_t)(b * C_ + c0)) * T_ + t0;
    unsigned short* xo = Xh + ((size_t)(b * C_ + c0)) * T_ + t0;
#pragma unroll
    for (int r = 0; r < 4; ++r) {
      int p = tid + r * 256;
      int row = p >> 4, c4 = (p & 15) << 2;
      float4 v = *(const float4*)&xin[(size_t)row * T_ + c4];
      unsigned short h0 = f2h(v.x), h1 = f2h(v.y), h2 = f2h(v.z), h3 = f2h(v.w);
      ushort4 hv; hv.x = h0; hv.y = h1; hv.z = h2; hv.w = h3;
      *(ushort4*)&xo[(size_t)row * T_ + c4] = hv;
      unsigned int lo = (unsigned int)h0 | ((unsigned int)h1 << 16);
      unsigned int hi = (unsigned int)h2 | ((unsigned int)h3 << 16);
      ((unsigned int*)&tile[row * PAD + c4])[0] = lo;
      ((unsigned int*)&tile[row * PAD + c4])[1] = hi;
      float s = v.x + v.y + v.z + v.w;
#pragma unroll
      for (int o = 1; o < 16; o <<= 1) s += __shfl_xor(s, o);
      if ((tid & 15) == 0) atomicAdd(&S[b * C_ + c0 + row], s);
    }
    __syncthreads();
#pragma unroll
    for (int r = 0; r < 2; ++r) {
      int idx = tid + r * 256;
      int trow = idx >> 3, cc = (idx & 7) << 3;
      unsigned short vals[8];
#pragma unroll
      for (int j = 0; j < 8; ++j) vals[j] = tile[(cc + j) * PAD + trow];
      *(uint4*)&XhT[((size_t)b * T_ + t0 + trow) * C_ + c0 + cc] = *(uint4*)vals;
    }
  } else {
    int i = (blockIdx.x - NXB) * 256 + tid;  // 0..C*C-1
    float q = Wq[i]; unsigned short qh = f2bf(q); Wqh[i] = qh; Wql[i] = f2bf(q - bf2f(qh));
    float k = Wk[i]; unsigned short kh = f2bf(k); Wkh[i] = kh; Wkl[i] = f2bf(k - bf2f(kh));
    float v = Wv[i]; int d = i >> 9, e = i & 511;
    WvT[(e << 9) + d] = f2h(v);
  }
}

// G: sum 4 splitK partials -> bf16 hi/lo
__global__ __launch_bounds__(256) void combine_g(const float* __restrict__ gp,
                                                 unsigned short* __restrict__ gh,
                                                 unsigned short* __restrict__ gl) {
  int i = blockIdx.x * 256 + threadIdx.x;
  int b = i >> 18, w = i & 0x3FFFF;
  const float* base = gp + ((size_t)b << 20);
  float v = base[w] + base[w + (1 << 18)] + base[w + 2 * (1 << 18)] + base[w + 3 * (1 << 18)];
  unsigned short h = f2bf(v);
  gh[i] = h;
  gl[i] = f2bf(v - bf2f(h));
}

// P: sum 2 partials -> bf16 hi/lo
__global__ __launch_bounds__(256) void combine_p(const float* __restrict__ pp,
                                                 unsigned short* __restrict__ ph,
                                                 unsigned short* __restrict__ pl) {
  int i = blockIdx.x * 256 + threadIdx.x;
  int b = i >> 18, w = i & 0x3FFFF;
  const float* base = pp + ((size_t)b << 19);
  float v = base[w] + base[w + (1 << 18)];
  unsigned short h = f2bf(v);
  ph[i] = h;
  pl[i] = f2bf(v - bf2f(h));
}

// M: sum 2 partials -> fp16
__global__ __launch_bounds__(256) void combine_m(const float* __restrict__ mp,
                                                 unsigned short* __restrict__ mh) {
  int i = blockIdx.x * 256 + threadIdx.x;
  int b = i >> 18, w = i & 0x3FFFF;
  const float* base = mp + ((size_t)b << 19);
  mh[i] = f2h(base[w] + base[w + (1 << 18)]);
}

// qs[b,i] = sum_c Wq[i,c] s[b,c];  ks[b,i] = sum_c Wk[i,c] s[b,c]
__global__ __launch_bounds__(256) void qs_ks(const float* __restrict__ Wq, const float* __restrict__ Wk,
                                             const float* __restrict__ s, float* __restrict__ qs,
                                             float* __restrict__ ks) {
  int lane = threadIdx.x & 63, wid = threadIdx.x >> 6;
  int gi = blockIdx.x * 4 + wid;
  int b = gi >> 9, i = gi & 511;
  const float* sv = s + (b << 9);
  const float* wqr = Wq + (size_t)i * C_;
  const float* wkr = Wk + (size_t)i * C_;
  float aq = 0.f, ak = 0.f;
#pragma unroll
  for (int c = lane; c < C_; c += 64) {
    float sc = sv[c];
    aq += wqr[c] * sc;
    ak += wkr[c] * sc;
  }
#pragma unroll
  for (int o = 32; o > 0; o >>= 1) { aq += __shfl_down(aq, o); ak += __shfl_down(ak, o); }
  if (lane == 0) { qs[gi] = aq; ks[gi] = ak; }
}

// Fused: combine logits partials + rank-1 bias terms + softmax -> attn fp16, ab.
__global__ __launch_bounds__(256) void combine_softmax(
    const float* __restrict__ lp, const float* __restrict__ qs,
    const float* __restrict__ ks, const float* __restrict__ bq,
    const float* __restrict__ bk, const float* __restrict__ bv,
    unsigned short* __restrict__ attn, float* __restrict__ ab) {
  const int row = blockIdx.x;            // b*512 + i
  const int b = row >> 9, i = row & 511;
  const int tid = threadIdx.x, lane = tid & 63, wid = tid >> 6;
  const float* p0 = lp + (((size_t)b << 19)) + ((size_t)i << 9);
  const float* p1 = p0 + (1 << 18);
  const float qsi = qs[row], bqi = bq[i];
  const int j0 = tid, j1 = tid + 256;
  float v0 = 0.125f * (p0[j0] + p1[j0] + qsi * bk[j0] + bqi * (ks[(b << 9) + j0] + 4096.f * bk[j0]));
  float v1 = 0.125f * (p0[j1] + p1[j1] + qsi * bk[j1] + bqi * (ks[(b << 9) + j1] + 4096.f * bk[j1]));
  __shared__ float red[4];
  float m = fmaxf(v0, v1);
#pragma unroll
  for (int o = 32; o > 0; o >>= 1) m = fmaxf(m, __shfl_down(m, o));
  if (lane == 0) red[wid] = m;
  __syncthreads();
  m = fmaxf(fmaxf(red[0], red[1]), fmaxf(red[2], red[3]));
  __syncthreads();
  float e0 = __expf(v0 - m), e1 = __expf(v1 - m);
  float sum = e0 + e1;
#pragma unroll
  for (int o = 32; o > 0; o >>= 1) sum += __shfl_down(sum, o);
  if (lane == 0) red[wid] = sum;
  __syncthreads();
  sum = red[0] + red[1] + red[2] + red[3];
  float inv = 1.f / sum;
  float a0 = e0 * inv, a1 = e1 * inv;
  unsigned short* ar = attn + (size_t)row * C_;
  ar[j0] = f2h(a0);
  ar[j1] = f2h(a1);
  float abv = a0 * bv[j0] + a1 * bv[j1];
  __syncthreads();
#pragma unroll
  for (int o = 32; o > 0; o >>= 1) abv += __shfl_down(abv, o);
  if (lane == 0) red[wid] = abv;
  __syncthreads();
  if (tid == 0) ab[row] = red[0] + red[1] + red[2] + red[3];
}

extern "C" void kernel_launch(void* const* d_in, const int* in_sizes, int n_in,
                              void* d_out, int out_size, void* d_ws, size_t ws_size,
                              hipStream_t stream) {
  const float* x  = (const float*)d_in[0];
  const float* Wq = (const float*)d_in[1];
  const float* bq = (const float*)d_in[2];
  const float* Wk = (const float*)d_in[3];
  const float* bk = (const float*)d_in[4];
  const float* Wv = (const float*)d_in[5];
  const float* bv = (const float*)d_in[6];
  float* out = (float*)d_out;

  char* ws = (char*)d_ws;
  size_t off = 0;
  auto alloc = [&](size_t bytes) {
    char* p = ws + off;
    off += (bytes + 255) & ~(size_t)255;
    return p;
  };
  const size_t XSZ = (size_t)B_ * C_ * T_;
  const size_t GSZ = (size_t)B_ * C_ * C_;   // 2^21

  // Xh region (dead after G gemm) later holds Mh + Attn.
  char* XhR = alloc(XSZ * 2);
  unsigned short* Xh   = (unsigned short*)XhR;
  unsigned short* Mh   = (unsigned short*)XhR;                  // after combine_m
  unsigned short* Attn = (unsigned short*)(XhR + GSZ * 4);      // after softmax
  unsigned short* XhT = (unsigned short*)alloc(XSZ * 2);
  // Gpart (4 splitK partials, 33.5 MB) later holds Ppart/Lpart/Mpart.
  float* Gpart = (float*)alloc((size_t)4 * GSZ * 4);
  float* Ppart = Gpart;                 // 2*GSZ floats
  float* Mpart = Gpart;                 // 2*GSZ floats (after combine_p)
  float* Lpart = Gpart + 2 * GSZ;       // 2*GSZ floats
  // Gh/Gl (dead after P gemm) later hold Ph/Pl.
  char* GhR = alloc(GSZ * 2);
  char* GlR = alloc(GSZ * 2);
  unsigned short* Gh = (unsigned short*)GhR;
  unsigned short* Gl = (unsigned short*)GlR;
  unsigned short* Ph = (unsigned short*)GhR;
  unsigned short* Pl = (unsigned short*)GlR;
  unsigned short* Wqh = (unsigned short*)alloc((size_t)C_ * C_ * 2);
  unsigned short* Wql = (unsigned short*)alloc((size_t)C_ * C_ * 2);
  unsigned short* Wkh = (unsigned short*)alloc((size_t)C_ * C_ * 2);
  unsigned short* Wkl = (unsigned short*)alloc((size_t)C_ * C_ * 2);
  unsigned short* WvT = (unsigned short*)alloc((size_t)C_ * C_ * 2);
  float* S  = (float*)alloc((size_t)B_ * C_ * 4);
  float* Qs = (float*)alloc((size_t)B_ * C_ * 4);
  float* Ks = (float*)alloc((size_t)B_ * C_ * 4);
  float* Ab = (float*)alloc((size_t)B_ * C_ * 4);

  hipMemsetAsync(S, 0, (size_t)B_ * C_ * 4, stream);
  prep_fused<<<NXB + C_ * C_ / 256, 256, 0, stream>>>(x, Wq, Wk, Wv, Xh, XhT, S,
                                                      Wqh, Wql, Wkh, Wkl, WvT);
  qs_ks<<<B_ * C_ / 4, 256, 0, stream>>>(Wq, Wk, S, Qs, Ks);

  {  // G = X X^T, fp16, splitK=4, 512-thread blocks (8 waves), KC=64
    GemmP p = {};
    p.Ah = Xh; p.sA = (long)C_ * T_; p.lda = T_;
    p.Bh = Xh; p.sB = (long)C_ * T_; p.ldb = T_;
    p.Cf = Gpart; p.sC = (long)C_ * C_; p.ldc = C_;
    p.kspan = T_ / 4; p.zparts = 4;
    gemm_nt<128, 128, 32, 64, 64, false, false, EPI_F32, true>
        <<<dim3(4, 4, 32), 512, 0, stream>>>(p);
  }
  combine_g<<<(int)(GSZ / 256), 256, 0, stream>>>(Gpart, Gh, Gl);

  {  // P = Wq G (bf16 hi/lo 3-pass), splitK=2
    GemmP p = {};
    p.Ah = Wqh; p.Al = Wql; p.sA = 0; p.lda = C_;
    p.Bh = Gh; p.Bl = Gl; p.sB = (long)C_ * C_; p.ldb = C_;
    p.Cf = Ppart; p.sC = (long)C_ * C_; p.ldc = C_;
    p.kspan = C_ / 2; p.zparts = 2;
    gemm_nt<64, 64, 32, 32, 32, true, true, EPI_F32, false>
        <<<dim3(8, 8, 16), 256, 0, stream>>>(p);
  }
  combine_p<<<(int)(GSZ / 256), 256, 0, stream>>>(Ppart, Ph, Pl);

  {  // logits partials = P Wk^T (bf16 hi/lo 3-pass), splitK=2
    GemmP p = {};
    p.Ah = Ph; p.Al = Pl; p.sA = (long)C_ * C_; p.lda = C_;
    p.Bh = Wkh; p.Bl = Wkl; p.sB = 0; p.ldb = C_;
    p.Cf = Lpart; p.sC = (long)C_ * C_; p.ldc = C_;
    p.kspan = C_ / 2; p.zparts = 2;
    gemm_nt<64, 64, 32, 32, 32, true, true, EPI_F32, false>
        <<<dim3(8, 8, 16), 256, 0, stream>>>(p);
  }
  combine_softmax<<<B_ * C_, 256, 0, stream>>>(Lpart, Qs, Ks, bq, bk, bv, Attn, Ab);

  {  // M partials = attn Wv (fp16, NT with WvT), splitK=2
    GemmP p = {};
    p.Ah = Attn; p.sA = (long)C_ * C_; p.lda = C_;
    p.Bh = WvT; p.sB = 0; p.ldb = C_;
    p.Cf = Mpart; p.sC = (long)C_ * C_; p.ldc = C_;
    p.kspan = C_ / 2; p.zparts = 2;
    gemm_nt<64, 64, 32, 32, 32, false, false, EPI_F32, true>
        <<<dim3(8, 8, 16), 256, 0, stream>>>(p);
  }
  combine_m<<<(int)(GSZ / 256), 256, 0, stream>>>(Mpart, Mh);

  {  // out = M X + ab (fp16, NT with XhT), KC=64
    GemmP p = {};
    p.Ah = Mh; p.sA = (long)C_ * C_; p.lda = C_;
    p.Bh = XhT; p.sB = (long)C_ * T_; p.ldb = C_;
    p.Cf = out; p.sC = (long)C_ * T_; p.ldc = T_;
    p.kspan = C_; p.zparts = 1;
    p.rowv = Ab;
    gemm_nt<128, 128, 64, 64, 64, false, false, EPI_OUT, true>
        <<<dim3(C_ / 128, T_ / 128, B_), 256, 0, stream>>>(p);
  }
  (void)in_sizes; (void)n_in; (void)out_size; (void)ws_size;
}

// Round 4
// 255.900 us; speedup vs baseline: 1.3126x; 1.0908x over previous
//
#include <hip/hip_runtime.h>

#define B_ 8
#define C_ 512
#define T_ 4096

typedef __attribute__((ext_vector_type(8))) __bf16 bf16x8;
typedef __attribute__((ext_vector_type(8))) _Float16 f16x8;
typedef __attribute__((ext_vector_type(8))) unsigned short u16x8;
typedef __attribute__((ext_vector_type(4))) float f32x4;

__device__ __forceinline__ unsigned short f2bf(float f) {
  unsigned int u = __float_as_uint(f);
  u += 0x7fffu + ((u >> 16) & 1u);   // RNE
  return (unsigned short)(u >> 16);
}
__device__ __forceinline__ float bf2f(unsigned short h) {
  return __uint_as_float(((unsigned int)h) << 16);
}
__device__ __forceinline__ unsigned short f2h(float f) {
  return __builtin_bit_cast(unsigned short, (_Float16)f);
}

__device__ __forceinline__ void async16(unsigned short* ldsdst, const unsigned short* gsrc) {
  __builtin_amdgcn_global_load_lds(
      (__attribute__((address_space(1))) void*)(void*)const_cast<unsigned short*>(gsrc),
      (__attribute__((address_space(3))) void*)(void*)ldsdst,
      16, 0, 0);
}

template <bool F16>
__device__ __forceinline__ f32x4 mfma16(u16x8 a, u16x8 b, f32x4 c) {
  if constexpr (F16)
    return __builtin_amdgcn_mfma_f32_16x16x32_f16(
        __builtin_bit_cast(f16x8, a), __builtin_bit_cast(f16x8, b), c, 0, 0, 0);
  else
    return __builtin_amdgcn_mfma_f32_16x16x32_bf16(
        __builtin_bit_cast(bf16x8, a), __builtin_bit_cast(bf16x8, b), c, 0, 0, 0);
}

struct GemmP {
  const unsigned short* Ah; const unsigned short* Al; long sA; int lda;
  const unsigned short* Bh; const unsigned short* Bl; long sB; int ldb;
  float* Cf; unsigned short* Ch; unsigned short* Cl; long sC; int ldc;
  int kspan; int zparts;
  const float* rowv; const float* colv; const float* bq; const float* bk;
};

enum { EPI_F32 = 0, EPI_OUT = 1, EPI_DOTS = 2, EPI_SPLIT = 3, EPI_F16 = 4 };

// NT GEMM: C[i][j] = sum_k A[i][k]*B[j][k]; optional hi/lo split (3-pass).
// KC=64. LDS layout XOR-swizzled per 16B chunk: global chunk c of row r is
// stored at slot (c ^ (r&7)) -> async writes stay lane-contiguous (legal for
// global_load_lds), fragment ds_read_b128 spreads quarter-wave lanes over 8
// bank groups (2-way aliasing = free) instead of 16-way same-bank.
// f32 epilogues staged via LDS (coalesced dwordx4); 16-bit epilogues direct.
template <int BM, int BN, int WM, int WN, bool SA, bool SB, int EPI, bool F16>
__global__ __launch_bounds__((BM / WM) * (BN / WN) * 64) void gemm_nt(GemmP g) {
  constexpr int KC = 64;
  constexpr int NWAVE = (BM / WM) * (BN / WN);
  constexpr int NT = NWAVE * 64;
  constexpr int ASZ = BM * KC, BSZ = BN * KC;
  constexpr int STAGE = (SA ? 2 : 1) * ASZ + (SB ? 2 : 1) * BSZ;  // shorts
  constexpr int EPAD = BN + 4;
  constexpr int EPIB = 32 * EPAD * 4;                              // bytes
  constexpr int LDSB = (STAGE * 2 > EPIB) ? STAGE * 2 : EPIB;
  __shared__ alignas(16) char ldsraw[LDSB];
  unsigned short* lds = (unsigned short*)ldsraw;
  unsigned short* ldsAh = lds;
  unsigned short* ldsAl = lds + ASZ;
  unsigned short* ldsBh = lds + (SA ? 2 : 1) * ASZ;
  unsigned short* ldsBl = ldsBh + BSZ;

  const int tid = threadIdx.x;
  const int lane = tid & 63, wid = tid >> 6;
  constexpr int WNB = BN / WN;
  const int wm = wid / WNB, wn = wid % WNB;
  constexpr int MF = WM / 16, NF = WN / 16;

  const int bm = blockIdx.x, bn = blockIdx.y, z = blockIdx.z;
  const int b = z / g.zparts, kp = z - b * g.zparts;

  const unsigned short* Ah = g.Ah + (size_t)b * g.sA + (size_t)kp * g.kspan;
  const unsigned short* Al = SA ? (g.Al + (size_t)b * g.sA + (size_t)kp * g.kspan) : nullptr;
  const unsigned short* Bh = g.Bh + (size_t)b * g.sB + (size_t)kp * g.kspan;
  const unsigned short* Bl = SB ? (g.Bl + (size_t)b * g.sB + (size_t)kp * g.kspan) : nullptr;

  f32x4 acc[MF][NF] = {};

  const int kIters = g.kspan / KC;
  for (int kt = 0; kt < kIters; ++kt) {
    const int kb = kt * KC;
#pragma unroll
    for (int r = 0; r < ASZ / (8 * NT); ++r) {
      int idx = tid + r * NT;
      int row = idx >> 3, sl = idx & 7;
      int kc = (sl ^ (row & 7)) << 3;                  // XOR swizzle
      size_t goff = (size_t)(bm * BM + row) * g.lda + kb + kc;
      async16(&ldsAh[idx << 3], Ah + goff);
      if constexpr (SA) async16(&ldsAl[idx << 3], Al + goff);
    }
#pragma unroll
    for (int r = 0; r < BSZ / (8 * NT); ++r) {
      int idx = tid + r * NT;
      int row = idx >> 3, sl = idx & 7;
      int kc = (sl ^ (row & 7)) << 3;
      size_t goff = (size_t)(bn * BN + row) * g.ldb + kb + kc;
      async16(&ldsBh[idx << 3], Bh + goff);
      if constexpr (SB) async16(&ldsBl[idx << 3], Bl + goff);
    }
    __syncthreads();

    const int rsel = lane & 15, kq = lane >> 4;
#pragma unroll
    for (int ks = 0; ks < KC; ks += 32) {
      const int chunk = (ks >> 3) + kq;
      u16x8 afh[MF], afl[MF], bfh[NF], bfl[NF];
#pragma unroll
      for (int fm = 0; fm < MF; ++fm) {
        int row = wm * WM + fm * 16 + rsel;
        int ro = row * KC + ((chunk ^ (row & 7)) << 3);
        afh[fm] = *(const u16x8*)&ldsAh[ro];
        if constexpr (SA) afl[fm] = *(const u16x8*)&ldsAl[ro];
      }
#pragma unroll
      for (int fn = 0; fn < NF; ++fn) {
        int row = wn * WN + fn * 16 + rsel;
        int ro = row * KC + ((chunk ^ (row & 7)) << 3);
        bfh[fn] = *(const u16x8*)&ldsBh[ro];
        if constexpr (SB) bfl[fn] = *(const u16x8*)&ldsBl[ro];
      }
#pragma unroll
      for (int fm = 0; fm < MF; ++fm)
#pragma unroll
        for (int fn = 0; fn < NF; ++fn) {
          acc[fm][fn] = mfma16<F16>(afh[fm], bfh[fn], acc[fm][fn]);
          if constexpr (SB) acc[fm][fn] = mfma16<F16>(afh[fm], bfl[fn], acc[fm][fn]);
          if constexpr (SA) acc[fm][fn] = mfma16<F16>(afl[fm], bfh[fn], acc[fm][fn]);
        }
    }
    __syncthreads();
  }

  if constexpr (EPI == EPI_SPLIT || EPI == EPI_F16) {
    // direct 16-bit scattered stores (small outputs)
#pragma unroll
    for (int fm = 0; fm < MF; ++fm)
#pragma unroll
      for (int fn = 0; fn < NF; ++fn)
#pragma unroll
        for (int r = 0; r < 4; ++r) {
          int i = bm * BM + wm * WM + fm * 16 + ((lane >> 4) << 2) + r;
          int j = bn * BN + wn * WN + fn * 16 + (lane & 15);
          float v = acc[fm][fn][r];
          size_t co = (size_t)z * g.sC + (size_t)i * g.ldc + j;
          if constexpr (EPI == EPI_SPLIT) {
            unsigned short h = f2bf(v);
            g.Ch[co] = h;
            g.Cl[co] = f2bf(v - bf2f(h));
          } else {
            g.Ch[co] = f2h(v);
          }
        }
  } else {
    // Chunked LDS epilogue: 32 rows x BN f32 per chunk, coalesced stores.
    // (requires WM==32 in all f32-epilogue instantiations)
    float* eb = (float*)ldsraw;
#pragma unroll
    for (int ck = 0; ck < BM / 32; ++ck) {
      if (wm == ck) {
#pragma unroll
        for (int fi = 0; fi < MF; ++fi) {
#pragma unroll
          for (int fn = 0; fn < NF; ++fn)
#pragma unroll
            for (int r = 0; r < 4; ++r) {
              int lrow = fi * 16 + ((lane >> 4) << 2) + r;
              int col = wn * WN + fn * 16 + (lane & 15);
              eb[lrow * EPAD + col] = acc[fi][fn][r];
            }
        }
      }
      __syncthreads();
#pragma unroll
      for (int it = 0; it < (32 * BN / 4) / NT; ++it) {
        int idx = it * NT + tid;
        int row = idx / (BN / 4), c4 = (idx % (BN / 4)) * 4;
        f32x4 v = *(f32x4*)&eb[row * EPAD + c4];
        int grow = bm * BM + ck * 32 + row;
        int j = bn * BN + c4;
        if constexpr (EPI == EPI_OUT) v = v + g.rowv[b * C_ + grow];
        if constexpr (EPI == EPI_DOTS) {
          f32x4 bkv = *(const f32x4*)&g.bk[j];
          f32x4 ksv = *(const f32x4*)&g.colv[b * C_ + j];
          float qsi = g.rowv[b * C_ + grow], bqi = g.bq[grow];
          v = 0.125f * (v + qsi * bkv + bqi * (ksv + 4096.f * bkv));
        }
        *(f32x4*)&g.Cf[(size_t)z * g.sC + (size_t)grow * g.ldc + j] = v;
      }
      __syncthreads();
    }
  }
}

// Fused prep: x tiles (fp32->fp16 Xh + XhT via LDS, row sums) + weight blocks.
#define NXB (64 * 8 * 8)
#define PAD 66
__global__ __launch_bounds__(256) void prep_fused(
    const float* __restrict__ x, const float* __restrict__ Wq,
    const float* __restrict__ Wk, const float* __restrict__ Wv,
    unsigned short* __restrict__ Xh, unsigned short* __restrict__ XhT,
    float* __restrict__ S, unsigned short* Wqh, unsigned short* Wql,
    unsigned short* Wkh, unsigned short* Wkl, unsigned short* WvT) {
  __shared__ unsigned short tile[64 * PAD];
  const int tid = threadIdx.x;
  if (blockIdx.x < NXB) {
    const int tl = blockIdx.x;
    const int t0 = (tl & 63) << 6, c0 = ((tl >> 6) & 7) << 6, b = tl >> 9;
    const float* xin = x + ((size_t)(b * C_ + c0)) * T_ + t0;
    unsigned short* xo = Xh + ((size_t)(b * C_ + c0)) * T_ + t0;
#pragma unroll
    for (int r = 0; r < 4; ++r) {
      int p = tid + r * 256;
      int row = p >> 4, c4 = (p & 15) << 2;
      float4 v = *(const float4*)&xin[(size_t)row * T_ + c4];
      unsigned short h0 = f2h(v.x), h1 = f2h(v.y), h2 = f2h(v.z), h3 = f2h(v.w);
      ushort4 hv; hv.x = h0; hv.y = h1; hv.z = h2; hv.w = h3;
      *(ushort4*)&xo[(size_t)row * T_ + c4] = hv;
      unsigned int lo = (unsigned int)h0 | ((unsigned int)h1 << 16);
      unsigned int hi = (unsigned int)h2 | ((unsigned int)h3 << 16);
      ((unsigned int*)&tile[row * PAD + c4])[0] = lo;
      ((unsigned int*)&tile[row * PAD + c4])[1] = hi;
      float s = v.x + v.y + v.z + v.w;
#pragma unroll
      for (int o = 1; o < 16; o <<= 1) s += __shfl_xor(s, o);
      if ((tid & 15) == 0) atomicAdd(&S[b * C_ + c0 + row], s);
    }
    __syncthreads();
#pragma unroll
    for (int r = 0; r < 2; ++r) {
      int idx = tid + r * 256;
      int trow = idx >> 3, cc = (idx & 7) << 3;
      unsigned short vals[8];
#pragma unroll
      for (int j = 0; j < 8; ++j) vals[j] = tile[(cc + j) * PAD + trow];
      *(uint4*)&XhT[((size_t)b * T_ + t0 + trow) * C_ + c0 + cc] = *(uint4*)vals;
    }
  } else {
    int i = (blockIdx.x - NXB) * 256 + tid;  // 0..C*C-1
    float q = Wq[i]; unsigned short qh = f2bf(q); Wqh[i] = qh; Wql[i] = f2bf(q - bf2f(qh));
    float k = Wk[i]; unsigned short kh = f2bf(k); Wkh[i] = kh; Wkl[i] = f2bf(k - bf2f(kh));
    float v = Wv[i]; int d = i >> 9, e = i & 511;
    WvT[(e << 9) + d] = f2h(v);
  }
}

// G: sum 4 splitK partials -> bf16 hi/lo
__global__ __launch_bounds__(256) void combine_g(const float* __restrict__ gp,
                                                 unsigned short* __restrict__ gh,
                                                 unsigned short* __restrict__ gl) {
  int i = blockIdx.x * 256 + threadIdx.x;
  int b = i >> 18, w = i & 0x3FFFF;
  const float* base = gp + ((size_t)b << 20);
  float v = base[w] + base[w + (1 << 18)] + base[w + 2 * (1 << 18)] + base[w + 3 * (1 << 18)];
  unsigned short h = f2bf(v);
  gh[i] = h;
  gl[i] = f2bf(v - bf2f(h));
}

// qs[b,i] = sum_c Wq[i,c] s[b,c];  ks[b,i] = sum_c Wk[i,c] s[b,c]
__global__ __launch_bounds__(256) void qs_ks(const float* __restrict__ Wq, const float* __restrict__ Wk,
                                             const float* __restrict__ s, float* __restrict__ qs,
                                             float* __restrict__ ks) {
  int lane = threadIdx.x & 63, wid = threadIdx.x >> 6;
  int gi = blockIdx.x * 4 + wid;
  int b = gi >> 9, i = gi & 511;
  const float* sv = s + (b << 9);
  const float* wqr = Wq + (size_t)i * C_;
  const float* wkr = Wk + (size_t)i * C_;
  float aq = 0.f, ak = 0.f;
#pragma unroll
  for (int c = lane; c < C_; c += 64) {
    float sc = sv[c];
    aq += wqr[c] * sc;
    ak += wkr[c] * sc;
  }
#pragma unroll
  for (int o = 32; o > 0; o >>= 1) { aq += __shfl_down(aq, o); ak += __shfl_down(ak, o); }
  if (lane == 0) { qs[gi] = aq; ks[gi] = ak; }
}

// rowwise softmax over 512 logits; attn fp16; ab[b,c] = sum_d attn*bv[d]
__global__ __launch_bounds__(256) void softmax_rows(const float* __restrict__ logits,
                                                    const float* __restrict__ bv,
                                                    unsigned short* __restrict__ attn,
                                                    float* __restrict__ ab) {
  const int row = blockIdx.x;
  const int tid = threadIdx.x, lane = tid & 63, wid = tid >> 6;
  const float* L = logits + (size_t)row * C_;
  float v0 = L[tid], v1 = L[tid + 256];
  __shared__ float red[4];
  float m = fmaxf(v0, v1);
#pragma unroll
  for (int o = 32; o > 0; o >>= 1) m = fmaxf(m, __shfl_down(m, o));
  if (lane == 0) red[wid] = m;
  __syncthreads();
  m = fmaxf(fmaxf(red[0], red[1]), fmaxf(red[2], red[3]));
  __syncthreads();
  float e0 = __expf(v0 - m), e1 = __expf(v1 - m);
  float sum = e0 + e1;
#pragma unroll
  for (int o = 32; o > 0; o >>= 1) sum += __shfl_down(sum, o);
  if (lane == 0) red[wid] = sum;
  __syncthreads();
  sum = red[0] + red[1] + red[2] + red[3];
  float inv = 1.f / sum;
  float a0 = e0 * inv, a1 = e1 * inv;
  unsigned short* ar = attn + (size_t)row * C_;
  ar[tid] = f2h(a0);
  ar[tid + 256] = f2h(a1);
  float abv = a0 * bv[tid] + a1 * bv[tid + 256];
  __syncthreads();
#pragma unroll
  for (int o = 32; o > 0; o >>= 1) abv += __shfl_down(abv, o);
  if (lane == 0) red[wid] = abv;
  __syncthreads();
  if (tid == 0) ab[row] = red[0] + red[1] + red[2] + red[3];
}

extern "C" void kernel_launch(void* const* d_in, const int* in_sizes, int n_in,
                              void* d_out, int out_size, void* d_ws, size_t ws_size,
                              hipStream_t stream) {
  const float* x  = (const float*)d_in[0];
  const float* Wq = (const float*)d_in[1];
  const float* bq = (const float*)d_in[2];
  const float* Wk = (const float*)d_in[3];
  const float* bk = (const float*)d_in[4];
  const float* Wv = (const float*)d_in[5];
  const float* bv = (const float*)d_in[6];
  float* out = (float*)d_out;

  char* ws = (char*)d_ws;
  size_t off = 0;
  auto alloc = [&](size_t bytes) {
    char* p = ws + off;
    off += (bytes + 255) & ~(size_t)255;
    return p;
  };
  const size_t XSZ = (size_t)B_ * C_ * T_;
  const size_t GSZ = (size_t)B_ * C_ * C_;   // 2^21

  unsigned short* Xh  = (unsigned short*)alloc(XSZ * 2);
  unsigned short* XhT = (unsigned short*)alloc(XSZ * 2);
  float* Gpart = (float*)alloc((size_t)4 * GSZ * 4);
  unsigned short* Gh = (unsigned short*)alloc(GSZ * 2);
  unsigned short* Gl = (unsigned short*)alloc(GSZ * 2);
  unsigned short* Ph = (unsigned short*)alloc(GSZ * 2);
  unsigned short* Pl = (unsigned short*)alloc(GSZ * 2);
  float* Logits = (float*)alloc(GSZ * 4);
  unsigned short* Attn = (unsigned short*)alloc(GSZ * 2);
  unsigned short* Mh = (unsigned short*)alloc(GSZ * 2);
  unsigned short* Wqh = (unsigned short*)alloc((size_t)C_ * C_ * 2);
  unsigned short* Wql = (unsigned short*)alloc((size_t)C_ * C_ * 2);
  unsigned short* Wkh = (unsigned short*)alloc((size_t)C_ * C_ * 2);
  unsigned short* Wkl = (unsigned short*)alloc((size_t)C_ * C_ * 2);
  unsigned short* WvT = (unsigned short*)alloc((size_t)C_ * C_ * 2);
  float* S  = (float*)alloc((size_t)B_ * C_ * 4);
  float* Qs = (float*)alloc((size_t)B_ * C_ * 4);
  float* Ks = (float*)alloc((size_t)B_ * C_ * 4);
  float* Ab = (float*)alloc((size_t)B_ * C_ * 4);

  hipMemsetAsync(S, 0, (size_t)B_ * C_ * 4, stream);
  prep_fused<<<NXB + C_ * C_ / 256, 256, 0, stream>>>(x, Wq, Wk, Wv, Xh, XhT, S,
                                                      Wqh, Wql, Wkh, Wkl, WvT);
  qs_ks<<<B_ * C_ / 4, 256, 0, stream>>>(Wq, Wk, S, Qs, Ks);

  {  // G = X X^T, fp16, splitK=4, 512-thread blocks (8 waves)
    GemmP p = {};
    p.Ah = Xh; p.sA = (long)C_ * T_; p.lda = T_;
    p.Bh = Xh; p.sB = (long)C_ * T_; p.ldb = T_;
    p.Cf = Gpart; p.sC = (long)C_ * C_; p.ldc = C_;
    p.kspan = T_ / 4; p.zparts = 4;
    gemm_nt<128, 128, 32, 64, false, false, EPI_F32, true>
        <<<dim3(4, 4, 32), 512, 0, stream>>>(p);
  }
  combine_g<<<(int)(GSZ / 256), 256, 0, stream>>>(Gpart, Gh, Gl);

  {  // P = Wq G (bf16 hi/lo 3-pass), direct split output
    GemmP p = {};
    p.Ah = Wqh; p.Al = Wql; p.sA = 0; p.lda = C_;
    p.Bh = Gh; p.Bl = Gl; p.sB = (long)C_ * C_; p.ldb = C_;
    p.Ch = Ph; p.Cl = Pl; p.sC = (long)C_ * C_; p.ldc = C_;
    p.kspan = C_; p.zparts = 1;
    gemm_nt<64, 64, 32, 32, true, true, EPI_SPLIT, false>
        <<<dim3(8, 8, 8), 256, 0, stream>>>(p);
  }
  {  // logits = 0.125*(P Wk^T + rank-1 bias terms), fp32, LDS-staged stores
    GemmP p = {};
    p.Ah = Ph; p.Al = Pl; p.sA = (long)C_ * C_; p.lda = C_;
    p.Bh = Wkh; p.Bl = Wkl; p.sB = 0; p.ldb = C_;
    p.Cf = Logits; p.sC = (long)C_ * C_; p.ldc = C_;
    p.kspan = C_; p.zparts = 1;
    p.rowv = Qs; p.colv = Ks; p.bq = bq; p.bk = bk;
    gemm_nt<64, 64, 32, 32, true, true, EPI_DOTS, false>
        <<<dim3(8, 8, 8), 256, 0, stream>>>(p);
  }
  softmax_rows<<<B_ * C_, 256, 0, stream>>>(Logits, bv, Attn, Ab);
  {  // M = attn Wv (fp16, NT with WvT), direct fp16 output
    GemmP p = {};
    p.Ah = Attn; p.sA = (long)C_ * C_; p.lda = C_;
    p.Bh = WvT; p.sB = 0; p.ldb = C_;
    p.Ch = Mh; p.sC = (long)C_ * C_; p.ldc = C_;
    p.kspan = C_; p.zparts = 1;
    gemm_nt<64, 64, 32, 32, false, false, EPI_F16, true>
        <<<dim3(8, 8, 8), 256, 0, stream>>>(p);
  }
  {  // out = M X + ab (fp16, NT with XhT), 512-thread blocks
    GemmP p = {};
    p.Ah = Mh; p.sA = (long)C_ * C_; p.lda = C_;
    p.Bh = XhT; p.sB = (long)C_ * T_; p.ldb = C_;
    p.Cf = out; p.sC = (long)C_ * T_; p.ldc = T_;
    p.kspan = C_; p.zparts = 1;
    p.rowv = Ab;
    gemm_nt<128, 128, 32, 64, false, false, EPI_OUT, true>
        <<<dim3(C_ / 128, T_ / 128, B_), 512, 0, stream>>>(p);
  }
  (void)in_sizes; (void)n_in; (void)out_size; (void)ws_size;
}

// Round 5
// 255.086 us; speedup vs baseline: 1.3167x; 1.0032x over previous
//
#include <hip/hip_runtime.h>

#define B_ 8
#define C_ 512
#define T_ 4096

typedef __attribute__((ext_vector_type(8))) __bf16 bf16x8;
typedef __attribute__((ext_vector_type(8))) _Float16 f16x8;
typedef __attribute__((ext_vector_type(8))) unsigned short u16x8;
typedef __attribute__((ext_vector_type(4))) float f32x4;

__device__ __forceinline__ unsigned short f2bf(float f) {
  unsigned int u = __float_as_uint(f);
  u += 0x7fffu + ((u >> 16) & 1u);   // RNE
  return (unsigned short)(u >> 16);
}
__device__ __forceinline__ float bf2f(unsigned short h) {
  return __uint_as_float(((unsigned int)h) << 16);
}
__device__ __forceinline__ unsigned short f2h(float f) {
  return __builtin_bit_cast(unsigned short, (_Float16)f);
}

__device__ __forceinline__ void async16(unsigned short* ldsdst, const unsigned short* gsrc) {
  __builtin_amdgcn_global_load_lds(
      (__attribute__((address_space(1))) void*)(void*)const_cast<unsigned short*>(gsrc),
      (__attribute__((address_space(3))) void*)(void*)ldsdst,
      16, 0, 0);
}

template <bool F16>
__device__ __forceinline__ f32x4 mfma16(u16x8 a, u16x8 b, f32x4 c) {
  if constexpr (F16)
    return __builtin_amdgcn_mfma_f32_16x16x32_f16(
        __builtin_bit_cast(f16x8, a), __builtin_bit_cast(f16x8, b), c, 0, 0, 0);
  else
    return __builtin_amdgcn_mfma_f32_16x16x32_bf16(
        __builtin_bit_cast(bf16x8, a), __builtin_bit_cast(bf16x8, b), c, 0, 0, 0);
}

struct GemmP {
  const unsigned short* Ah; const unsigned short* Al; long sA; int lda;
  const unsigned short* Bh; const unsigned short* Bl; long sB; int ldb;
  float* Cf; unsigned short* Ch; unsigned short* Cl; long sC; int ldc;
  int kspan; int zparts;
  const float* rowv; const float* colv; const float* bq; const float* bk;
};

enum { EPI_F32 = 0, EPI_OUT = 1, EPI_DOTS = 2, EPI_SPLIT = 3, EPI_F16 = 4 };

// NT GEMM: C[i][j] = sum_k A[i][k]*B[j][k]; optional hi/lo split (3-pass).
// KC=64, XOR-swizzled 16B chunks (conflict-free ds_read_b128 + legal
// global_load_lds). TRI: blockIdx.x enumerates lower-triangle 128-tiles of a
// 4x4 tile grid (G = X X^T symmetry). f32 epilogues staged via LDS.
template <int BM, int BN, int WM, int WN, bool SA, bool SB, int EPI, bool F16, bool TRI>
__global__ __launch_bounds__((BM / WM) * (BN / WN) * 64) void gemm_nt(GemmP g) {
  constexpr int KC = 64;
  constexpr int NWAVE = (BM / WM) * (BN / WN);
  constexpr int NT = NWAVE * 64;
  constexpr int ASZ = BM * KC, BSZ = BN * KC;
  constexpr int STAGE = (SA ? 2 : 1) * ASZ + (SB ? 2 : 1) * BSZ;  // shorts
  constexpr int EPAD = BN + 4;
  constexpr int EPIB = 32 * EPAD * 4;                              // bytes
  constexpr int LDSB = (STAGE * 2 > EPIB) ? STAGE * 2 : EPIB;
  __shared__ alignas(16) char ldsraw[LDSB];
  unsigned short* lds = (unsigned short*)ldsraw;
  unsigned short* ldsAh = lds;
  unsigned short* ldsAl = lds + ASZ;
  unsigned short* ldsBh = lds + (SA ? 2 : 1) * ASZ;
  unsigned short* ldsBl = ldsBh + BSZ;

  const int tid = threadIdx.x;
  const int lane = tid & 63, wid = tid >> 6;
  constexpr int WNB = BN / WN;
  const int wm = wid / WNB, wn = wid % WNB;
  constexpr int MF = WM / 16, NF = WN / 16;

  int bm, bn;
  if constexpr (TRI) {
    const int t = blockIdx.x;  // 0..9 -> lower-triangle (bm,bn) of 4x4
    const int tm = (t >= 6) ? 3 : (t >= 3) ? 2 : (t >= 1) ? 1 : 0;
    bm = tm; bn = t - (tm * (tm + 1)) / 2;
  } else {
    bm = blockIdx.x; bn = blockIdx.y;
  }
  const int z = blockIdx.z;
  const int b = z / g.zparts, kp = z - b * g.zparts;

  const unsigned short* Ah = g.Ah + (size_t)b * g.sA + (size_t)kp * g.kspan;
  const unsigned short* Al = SA ? (g.Al + (size_t)b * g.sA + (size_t)kp * g.kspan) : nullptr;
  const unsigned short* Bh = g.Bh + (size_t)b * g.sB + (size_t)kp * g.kspan;
  const unsigned short* Bl = SB ? (g.Bl + (size_t)b * g.sB + (size_t)kp * g.kspan) : nullptr;

  f32x4 acc[MF][NF] = {};

  const int kIters = g.kspan / KC;
  for (int kt = 0; kt < kIters; ++kt) {
    const int kb = kt * KC;
#pragma unroll
    for (int r = 0; r < ASZ / (8 * NT); ++r) {
      int idx = tid + r * NT;
      int row = idx >> 3, sl = idx & 7;
      int kc = (sl ^ (row & 7)) << 3;                  // XOR swizzle
      size_t goff = (size_t)(bm * BM + row) * g.lda + kb + kc;
      async16(&ldsAh[idx << 3], Ah + goff);
      if constexpr (SA) async16(&ldsAl[idx << 3], Al + goff);
    }
#pragma unroll
    for (int r = 0; r < BSZ / (8 * NT); ++r) {
      int idx = tid + r * NT;
      int row = idx >> 3, sl = idx & 7;
      int kc = (sl ^ (row & 7)) << 3;
      size_t goff = (size_t)(bn * BN + row) * g.ldb + kb + kc;
      async16(&ldsBh[idx << 3], Bh + goff);
      if constexpr (SB) async16(&ldsBl[idx << 3], Bl + goff);
    }
    __syncthreads();

    const int rsel = lane & 15, kq = lane >> 4;
#pragma unroll
    for (int ks = 0; ks < KC; ks += 32) {
      const int chunk = (ks >> 3) + kq;
      u16x8 afh[MF], afl[MF], bfh[NF], bfl[NF];
#pragma unroll
      for (int fm = 0; fm < MF; ++fm) {
        int row = wm * WM + fm * 16 + rsel;
        int ro = row * KC + ((chunk ^ (row & 7)) << 3);
        afh[fm] = *(const u16x8*)&ldsAh[ro];
        if constexpr (SA) afl[fm] = *(const u16x8*)&ldsAl[ro];
      }
#pragma unroll
      for (int fn = 0; fn < NF; ++fn) {
        int row = wn * WN + fn * 16 + rsel;
        int ro = row * KC + ((chunk ^ (row & 7)) << 3);
        bfh[fn] = *(const u16x8*)&ldsBh[ro];
        if constexpr (SB) bfl[fn] = *(const u16x8*)&ldsBl[ro];
      }
#pragma unroll
      for (int fm = 0; fm < MF; ++fm)
#pragma unroll
        for (int fn = 0; fn < NF; ++fn) {
          acc[fm][fn] = mfma16<F16>(afh[fm], bfh[fn], acc[fm][fn]);
          if constexpr (SB) acc[fm][fn] = mfma16<F16>(afh[fm], bfl[fn], acc[fm][fn]);
          if constexpr (SA) acc[fm][fn] = mfma16<F16>(afl[fm], bfh[fn], acc[fm][fn]);
        }
    }
    __syncthreads();
  }

  if constexpr (EPI == EPI_SPLIT || EPI == EPI_F16) {
    // direct 16-bit scattered stores (small outputs)
#pragma unroll
    for (int fm = 0; fm < MF; ++fm)
#pragma unroll
      for (int fn = 0; fn < NF; ++fn)
#pragma unroll
        for (int r = 0; r < 4; ++r) {
          int i = bm * BM + wm * WM + fm * 16 + ((lane >> 4) << 2) + r;
          int j = bn * BN + wn * WN + fn * 16 + (lane & 15);
          float v = acc[fm][fn][r];
          size_t co = (size_t)z * g.sC + (size_t)i * g.ldc + j;
          if constexpr (EPI == EPI_SPLIT) {
            unsigned short h = f2bf(v);
            g.Ch[co] = h;
            g.Cl[co] = f2bf(v - bf2f(h));
          } else {
            g.Ch[co] = f2h(v);
          }
        }
  } else {
    // Chunked LDS epilogue: 32 rows x BN f32 per chunk, coalesced stores.
    float* eb = (float*)ldsraw;
#pragma unroll
    for (int ck = 0; ck < BM / 32; ++ck) {
      if (wm == (ck * 32) / WM) {
        const int fm0 = ((ck * 32) % WM) / 16;
#pragma unroll
        for (int fi = 0; fi < 2; ++fi) {
          int fm = fm0 + fi;
#pragma unroll
          for (int fn = 0; fn < NF; ++fn)
#pragma unroll
            for (int r = 0; r < 4; ++r) {
              int lrow = fi * 16 + ((lane >> 4) << 2) + r;
              int col = wn * WN + fn * 16 + (lane & 15);
              eb[lrow * EPAD + col] = acc[fm][fn][r];
            }
        }
      }
      __syncthreads();
#pragma unroll
      for (int it = 0; it < (32 * BN / 4) / NT; ++it) {
        int idx = it * NT + tid;
        int row = idx / (BN / 4), c4 = (idx % (BN / 4)) * 4;
        f32x4 v = *(f32x4*)&eb[row * EPAD + c4];
        int grow = bm * BM + ck * 32 + row;
        int j = bn * BN + c4;
        if constexpr (EPI == EPI_OUT) v = v + g.rowv[b * C_ + grow];
        if constexpr (EPI == EPI_DOTS) {
          f32x4 bkv = *(const f32x4*)&g.bk[j];
          f32x4 ksv = *(const f32x4*)&g.colv[b * C_ + j];
          float qsi = g.rowv[b * C_ + grow], bqi = g.bq[grow];
          v = 0.125f * (v + qsi * bkv + bqi * (ksv + 4096.f * bkv));
        }
        *(f32x4*)&g.Cf[(size_t)z * g.sC + (size_t)grow * g.ldc + j] = v;
      }
      __syncthreads();
    }
  }
}

// Fused prep: x tiles (fp32->fp16 Xh + XhT via LDS, row sums) + weight blocks.
#define NXB (64 * 8 * 8)
#define PAD 66
__global__ __launch_bounds__(256) void prep_fused(
    const float* __restrict__ x, const float* __restrict__ Wq,
    const float* __restrict__ Wk, const float* __restrict__ Wv,
    unsigned short* __restrict__ Xh, unsigned short* __restrict__ XhT,
    float* __restrict__ S, unsigned short* Wqh, unsigned short* Wql,
    unsigned short* Wkh, unsigned short* Wkl, unsigned short* WvT) {
  __shared__ unsigned short tile[64 * PAD];
  const int tid = threadIdx.x;
  if (blockIdx.x < NXB) {
    const int tl = blockIdx.x;
    const int t0 = (tl & 63) << 6, c0 = ((tl >> 6) & 7) << 6, b = tl >> 9;
    const float* xin = x + ((size_t)(b * C_ + c0)) * T_ + t0;
    unsigned short* xo = Xh + ((size_t)(b * C_ + c0)) * T_ + t0;
#pragma unroll
    for (int r = 0; r < 4; ++r) {
      int p = tid + r * 256;
      int row = p >> 4, c4 = (p & 15) << 2;
      float4 v = *(const float4*)&xin[(size_t)row * T_ + c4];
      unsigned short h0 = f2h(v.x), h1 = f2h(v.y), h2 = f2h(v.z), h3 = f2h(v.w);
      ushort4 hv; hv.x = h0; hv.y = h1; hv.z = h2; hv.w = h3;
      *(ushort4*)&xo[(size_t)row * T_ + c4] = hv;
      unsigned int lo = (unsigned int)h0 | ((unsigned int)h1 << 16);
      unsigned int hi = (unsigned int)h2 | ((unsigned int)h3 << 16);
      ((unsigned int*)&tile[row * PAD + c4])[0] = lo;
      ((unsigned int*)&tile[row * PAD + c4])[1] = hi;
      float s = v.x + v.y + v.z + v.w;
#pragma unroll
      for (int o = 1; o < 16; o <<= 1) s += __shfl_xor(s, o);
      if ((tid & 15) == 0) atomicAdd(&S[b * C_ + c0 + row], s);
    }
    __syncthreads();
#pragma unroll
    for (int r = 0; r < 2; ++r) {
      int idx = tid + r * 256;
      int trow = idx >> 3, cc = (idx & 7) << 3;
      unsigned short vals[8];
#pragma unroll
      for (int j = 0; j < 8; ++j) vals[j] = tile[(cc + j) * PAD + trow];
      *(uint4*)&XhT[((size_t)b * T_ + t0 + trow) * C_ + c0 + cc] = *(uint4*)vals;
    }
  } else {
    int i = (blockIdx.x - NXB) * 256 + tid;  // 0..C*C-1
    float q = Wq[i]; unsigned short qh = f2bf(q); Wqh[i] = qh; Wql[i] = f2bf(q - bf2f(qh));
    float k = Wk[i]; unsigned short kh = f2bf(k); Wkh[i] = kh; Wkl[i] = f2bf(k - bf2f(kh));
    float v = Wv[i]; int d = i >> 9, e = i & 511;
    WvT[(e << 9) + d] = f2h(v);
  }
}

// G combine: sum 8 splitK partials from the lower-triangle source tile
// (transposing via LDS for mirrored upper tiles) -> bf16 hi/lo full square.
__global__ __launch_bounds__(256) void combine_g(const float* __restrict__ gp,
                                                 unsigned short* __restrict__ gh,
                                                 unsigned short* __restrict__ gl) {
  __shared__ float tile[64 * 65];
  const int blk = blockIdx.x;             // b*64 + tr*8 + tc  (64x64 out tiles)
  const int b = blk >> 6, tr = (blk >> 3) & 7, tc = blk & 7;
  const bool mirror = (tr >> 1) < (tc >> 1);      // containing 128-tile is upper
  const int sr = mirror ? tc : tr, sc = mirror ? tr : tc;
  const float* src = gp + ((size_t)b << 21) + (size_t)(sr << 6) * 512 + (sc << 6);
  const int row = threadIdx.x >> 4, c4 = (threadIdx.x & 15) << 2;
  float vals[4][4];
#pragma unroll
  for (int rr = 0; rr < 4; ++rr) {
    const int r = row + rr * 16;
    f32x4 v = {};
#pragma unroll
    for (int p = 0; p < 8; ++p)
      v += *(const f32x4*)&src[((size_t)p << 18) + (size_t)r * 512 + c4];
    if (mirror) {
#pragma unroll
      for (int k = 0; k < 4; ++k) tile[r * 65 + c4 + k] = v[k];
    } else {
#pragma unroll
      for (int k = 0; k < 4; ++k) vals[rr][k] = v[k];
    }
  }
  if (mirror) {
    __syncthreads();
#pragma unroll
    for (int rr = 0; rr < 4; ++rr) {
      const int r = row + rr * 16;
#pragma unroll
      for (int k = 0; k < 4; ++k) vals[rr][k] = tile[(c4 + k) * 65 + r];
    }
  }
  unsigned short* ghp = gh + ((size_t)b << 18) + (size_t)(tr << 6) * 512 + (tc << 6);
  unsigned short* glp = gl + ((size_t)b << 18) + (size_t)(tr << 6) * 512 + (tc << 6);
#pragma unroll
  for (int rr = 0; rr < 4; ++rr) {
    const int r = row + rr * 16;
    ushort4 h, l;
    h.x = f2bf(vals[rr][0]); l.x = f2bf(vals[rr][0] - bf2f(h.x));
    h.y = f2bf(vals[rr][1]); l.y = f2bf(vals[rr][1] - bf2f(h.y));
    h.z = f2bf(vals[rr][2]); l.z = f2bf(vals[rr][2] - bf2f(h.z));
    h.w = f2bf(vals[rr][3]); l.w = f2bf(vals[rr][3] - bf2f(h.w));
    *(ushort4*)&ghp[(size_t)r * 512 + c4] = h;
    *(ushort4*)&glp[(size_t)r * 512 + c4] = l;
  }
}

// qs[b,i] = sum_c Wq[i,c] s[b,c];  ks[b,i] = sum_c Wk[i,c] s[b,c]
__global__ __launch_bounds__(256) void qs_ks(const float* __restrict__ Wq, const float* __restrict__ Wk,
                                             const float* __restrict__ s, float* __restrict__ qs,
                                             float* __restrict__ ks) {
  int lane = threadIdx.x & 63, wid = threadIdx.x >> 6;
  int gi = blockIdx.x * 4 + wid;
  int b = gi >> 9, i = gi & 511;
  const float* sv = s + (b << 9);
  const float* wqr = Wq + (size_t)i * C_;
  const float* wkr = Wk + (size_t)i * C_;
  float aq = 0.f, ak = 0.f;
#pragma unroll
  for (int c = lane; c < C_; c += 64) {
    float sc = sv[c];
    aq += wqr[c] * sc;
    ak += wkr[c] * sc;
  }
#pragma unroll
  for (int o = 32; o > 0; o >>= 1) { aq += __shfl_down(aq, o); ak += __shfl_down(ak, o); }
  if (lane == 0) { qs[gi] = aq; ks[gi] = ak; }
}

// rowwise softmax over 512 logits; attn fp16; ab[b,c] = sum_d attn*bv[d]
__global__ __launch_bounds__(256) void softmax_rows(const float* __restrict__ logits,
                                                    const float* __restrict__ bv,
                                                    unsigned short* __restrict__ attn,
                                                    float* __restrict__ ab) {
  const int row = blockIdx.x;
  const int tid = threadIdx.x, lane = tid & 63, wid = tid >> 6;
  const float* L = logits + (size_t)row * C_;
  float v0 = L[tid], v1 = L[tid + 256];
  __shared__ float red[4];
  float m = fmaxf(v0, v1);
#pragma unroll
  for (int o = 32; o > 0; o >>= 1) m = fmaxf(m, __shfl_down(m, o));
  if (lane == 0) red[wid] = m;
  __syncthreads();
  m = fmaxf(fmaxf(red[0], red[1]), fmaxf(red[2], red[3]));
  __syncthreads();
  float e0 = __expf(v0 - m), e1 = __expf(v1 - m);
  float sum = e0 + e1;
#pragma unroll
  for (int o = 32; o > 0; o >>= 1) sum += __shfl_down(sum, o);
  if (lane == 0) red[wid] = sum;
  __syncthreads();
  sum = red[0] + red[1] + red[2] + red[3];
  float inv = 1.f / sum;
  float a0 = e0 * inv, a1 = e1 * inv;
  unsigned short* ar = attn + (size_t)row * C_;
  ar[tid] = f2h(a0);
  ar[tid + 256] = f2h(a1);
  float abv = a0 * bv[tid] + a1 * bv[tid + 256];
  __syncthreads();
#pragma unroll
  for (int o = 32; o > 0; o >>= 1) abv += __shfl_down(abv, o);
  if (lane == 0) red[wid] = abv;
  __syncthreads();
  if (tid == 0) ab[row] = red[0] + red[1] + red[2] + red[3];
}

extern "C" void kernel_launch(void* const* d_in, const int* in_sizes, int n_in,
                              void* d_out, int out_size, void* d_ws, size_t ws_size,
                              hipStream_t stream) {
  const float* x  = (const float*)d_in[0];
  const float* Wq = (const float*)d_in[1];
  const float* bq = (const float*)d_in[2];
  const float* Wk = (const float*)d_in[3];
  const float* bk = (const float*)d_in[4];
  const float* Wv = (const float*)d_in[5];
  const float* bv = (const float*)d_in[6];
  float* out = (float*)d_out;

  char* ws = (char*)d_ws;
  size_t off = 0;
  auto alloc = [&](size_t bytes) {
    char* p = ws + off;
    off += (bytes + 255) & ~(size_t)255;
    return p;
  };
  const size_t XSZ = (size_t)B_ * C_ * T_;
  const size_t GSZ = (size_t)B_ * C_ * C_;   // 2^21

  unsigned short* Xh  = (unsigned short*)alloc(XSZ * 2);
  unsigned short* XhT = (unsigned short*)alloc(XSZ * 2);
  float* Gpart = (float*)alloc((size_t)8 * GSZ * 4);   // 67 MB (8 splitK parts)
  unsigned short* Gh = (unsigned short*)alloc(GSZ * 2);
  unsigned short* Gl = (unsigned short*)alloc(GSZ * 2);
  unsigned short* Ph = (unsigned short*)alloc(GSZ * 2);
  unsigned short* Pl = (unsigned short*)alloc(GSZ * 2);
  float* Logits = (float*)alloc(GSZ * 4);
  unsigned short* Attn = (unsigned short*)alloc(GSZ * 2);
  unsigned short* Mh = (unsigned short*)alloc(GSZ * 2);
  unsigned short* Wqh = (unsigned short*)alloc((size_t)C_ * C_ * 2);
  unsigned short* Wql = (unsigned short*)alloc((size_t)C_ * C_ * 2);
  unsigned short* Wkh = (unsigned short*)alloc((size_t)C_ * C_ * 2);
  unsigned short* Wkl = (unsigned short*)alloc((size_t)C_ * C_ * 2);
  unsigned short* WvT = (unsigned short*)alloc((size_t)C_ * C_ * 2);
  float* S  = (float*)alloc((size_t)B_ * C_ * 4);
  float* Qs = (float*)alloc((size_t)B_ * C_ * 4);
  float* Ks = (float*)alloc((size_t)B_ * C_ * 4);
  float* Ab = (float*)alloc((size_t)B_ * C_ * 4);

  hipMemsetAsync(S, 0, (size_t)B_ * C_ * 4, stream);
  prep_fused<<<NXB + C_ * C_ / 256, 256, 0, stream>>>(x, Wq, Wk, Wv, Xh, XhT, S,
                                                      Wqh, Wql, Wkh, Wkl, WvT);
  qs_ks<<<B_ * C_ / 4, 256, 0, stream>>>(Wq, Wk, S, Qs, Ks);

  {  // G = X X^T, fp16, lower-triangle 128-tiles only, splitK=8
    GemmP p = {};
    p.Ah = Xh; p.sA = (long)C_ * T_; p.lda = T_;
    p.Bh = Xh; p.sB = (long)C_ * T_; p.ldb = T_;
    p.Cf = Gpart; p.sC = (long)C_ * C_; p.ldc = C_;
    p.kspan = T_ / 8; p.zparts = 8;
    gemm_nt<128, 128, 32, 64, false, false, EPI_F32, true, true>
        <<<dim3(10, 1, 64), 512, 0, stream>>>(p);
  }
  combine_g<<<B_ * 64, 256, 0, stream>>>(Gpart, Gh, Gl);

  {  // P = Wq G (bf16 hi/lo 3-pass), direct split output
    GemmP p = {};
    p.Ah = Wqh; p.Al = Wql; p.sA = 0; p.lda = C_;
    p.Bh = Gh; p.Bl = Gl; p.sB = (long)C_ * C_; p.ldb = C_;
    p.Ch = Ph; p.Cl = Pl; p.sC = (long)C_ * C_; p.ldc = C_;
    p.kspan = C_; p.zparts = 1;
    gemm_nt<64, 64, 32, 32, true, true, EPI_SPLIT, false, false>
        <<<dim3(8, 8, 8), 256, 0, stream>>>(p);
  }
  {  // logits = 0.125*(P Wk^T + rank-1 bias terms), fp32, LDS-staged stores
    GemmP p = {};
    p.Ah = Ph; p.Al = Pl; p.sA = (long)C_ * C_; p.lda = C_;
    p.Bh = Wkh; p.Bl = Wkl; p.sB = 0; p.ldb = C_;
    p.Cf = Logits; p.sC = (long)C_ * C_; p.ldc = C_;
    p.kspan = C_; p.zparts = 1;
    p.rowv = Qs; p.colv = Ks; p.bq = bq; p.bk = bk;
    gemm_nt<64, 64, 32, 32, true, true, EPI_DOTS, false, false>
        <<<dim3(8, 8, 8), 256, 0, stream>>>(p);
  }
  softmax_rows<<<B_ * C_, 256, 0, stream>>>(Logits, bv, Attn, Ab);
  {  // M = attn Wv (fp16, NT with WvT), direct fp16 output
    GemmP p = {};
    p.Ah = Attn; p.sA = (long)C_ * C_; p.lda = C_;
    p.Bh = WvT; p.sB = 0; p.ldb = C_;
    p.Ch = Mh; p.sC = (long)C_ * C_; p.ldc = C_;
    p.kspan = C_; p.zparts = 1;
    gemm_nt<64, 64, 32, 32, false, false, EPI_F16, true, false>
        <<<dim3(8, 8, 8), 256, 0, stream>>>(p);
  }
  {  // out = M X + ab (fp16, NT with XhT), 4-wave 128x128 blocks
    GemmP p = {};
    p.Ah = Mh; p.sA = (long)C_ * C_; p.lda = C_;
    p.Bh = XhT; p.sB = (long)C_ * T_; p.ldb = C_;
    p.Cf = out; p.sC = (long)C_ * T_; p.ldc = T_;
    p.kspan = C_; p.zparts = 1;
    p.rowv = Ab;
    gemm_nt<128, 128, 64, 64, false, false, EPI_OUT, true, false>
        <<<dim3(C_ / 128, T_ / 128, B_), 256, 0, stream>>>(p);
  }
  (void)in_sizes; (void)n_in; (void)out_size; (void)ws_size;
}

// Round 6
// 233.984 us; speedup vs baseline: 1.4355x; 1.0902x over previous
//
#include <hip/hip_runtime.h>

#define B_ 8
#define C_ 512
#define T_ 4096

typedef __attribute__((ext_vector_type(8))) __bf16 bf16x8;
typedef __attribute__((ext_vector_type(8))) _Float16 f16x8;
typedef __attribute__((ext_vector_type(8))) unsigned short u16x8;
typedef __attribute__((ext_vector_type(4))) float f32x4;

__device__ __forceinline__ unsigned short f2bf(float f) {
  unsigned int u = __float_as_uint(f);
  u += 0x7fffu + ((u >> 16) & 1u);   // RNE
  return (unsigned short)(u >> 16);
}
__device__ __forceinline__ float bf2f(unsigned short h) {
  return __uint_as_float(((unsigned int)h) << 16);
}
__device__ __forceinline__ unsigned short f2h(float f) {
  return __builtin_bit_cast(unsigned short, (_Float16)f);
}

__device__ __forceinline__ void async16(unsigned short* ldsdst, const unsigned short* gsrc) {
  __builtin_amdgcn_global_load_lds(
      (__attribute__((address_space(1))) void*)(void*)const_cast<unsigned short*>(gsrc),
      (__attribute__((address_space(3))) void*)(void*)ldsdst,
      16, 0, 0);
}

template <bool F16>
__device__ __forceinline__ f32x4 mfma16(u16x8 a, u16x8 b, f32x4 c) {
  if constexpr (F16)
    return __builtin_amdgcn_mfma_f32_16x16x32_f16(
        __builtin_bit_cast(f16x8, a), __builtin_bit_cast(f16x8, b), c, 0, 0, 0);
  else
    return __builtin_amdgcn_mfma_f32_16x16x32_bf16(
        __builtin_bit_cast(bf16x8, a), __builtin_bit_cast(bf16x8, b), c, 0, 0, 0);
}

struct GemmP {
  const unsigned short* Ah; const unsigned short* Al; long sA; int lda;
  const unsigned short* Bh; const unsigned short* Bl; long sB; int ldb;
  float* Cf; unsigned short* Ch; unsigned short* Cl; long sC; int ldc;
  int kspan; int zparts;
  const float* rowv; const float* colv; const float* bq; const float* bk;
};

enum { EPI_F32 = 0, EPI_OUT = 1, EPI_DOTS = 2, EPI_SPLIT = 3, EPI_F16 = 4 };
// SWZ: 0 = 3D grid (x,y,z); 1 = G-triangle linear grid, kp%8 -> XCD;
//      2 = out linear grid, T-tile%8 -> XCD.

// NT GEMM: C[i][j] = sum_k A[i][k]*B[j][k]; optional hi/lo split (3-pass).
// KC=64, XOR-swizzled 16B chunks (conflict-free ds_read_b128 + legal
// global_load_lds). f32 epilogues staged via LDS for coalesced dwordx4.
template <int BM, int BN, int WM, int WN, bool SA, bool SB, int EPI, bool F16, int SWZ>
__global__ __launch_bounds__((BM / WM) * (BN / WN) * 64) void gemm_nt(GemmP g) {
  constexpr int KC = 64;
  constexpr int NWAVE = (BM / WM) * (BN / WN);
  constexpr int NT = NWAVE * 64;
  constexpr int ASZ = BM * KC, BSZ = BN * KC;
  constexpr int STAGE = (SA ? 2 : 1) * ASZ + (SB ? 2 : 1) * BSZ;  // shorts
  constexpr int EPAD = BN + 4;
  constexpr int EPIB = 32 * EPAD * 4;                              // bytes
  constexpr int LDSB = (STAGE * 2 > EPIB) ? STAGE * 2 : EPIB;
  __shared__ alignas(16) char ldsraw[LDSB];
  unsigned short* lds = (unsigned short*)ldsraw;
  unsigned short* ldsAh = lds;
  unsigned short* ldsAl = lds + ASZ;
  unsigned short* ldsBh = lds + (SA ? 2 : 1) * ASZ;
  unsigned short* ldsBl = ldsBh + BSZ;

  const int tid = threadIdx.x;
  const int lane = tid & 63, wid = tid >> 6;
  constexpr int WNB = BN / WN;
  const int wm = wid / WNB, wn = wid % WNB;
  constexpr int MF = WM / 16, NF = WN / 16;

  int bm, bn, z;
  if constexpr (SWZ == 1) {
    // 640 blocks: r=kp (XCD), zq=batch, tri = lower-triangle 128-tile of 4x4
    const int blk = blockIdx.x;
    const int r = blk & 7, q = blk >> 3;       // q 0..79
    const int tri = q % 10, zq = q / 10;
    const int tm = (tri >= 6) ? 3 : (tri >= 3) ? 2 : (tri >= 1) ? 1 : 0;
    bm = tm; bn = tri - (tm * (tm + 1)) / 2;
    z = zq * 8 + r;                            // b = zq, kp = r
  } else if constexpr (SWZ == 2) {
    // 512 blocks: r = T-tile low bits (XCD) -> XhT slice L2-resident per XCD
    const int blk = blockIdx.x;
    const int r = blk & 7, q = blk >> 3;       // q 0..63
    bm = q & 3;
    const int w = q >> 2;                      // 0..15
    bn = ((w & 1) << 3) + r;                   // 0..15
    z = w >> 1;                                // batch 0..7
  } else {
    bm = blockIdx.x; bn = blockIdx.y; z = blockIdx.z;
  }
  const int b = z / g.zparts, kp = z - b * g.zparts;

  const unsigned short* Ah = g.Ah + (size_t)b * g.sA + (size_t)kp * g.kspan;
  const unsigned short* Al = SA ? (g.Al + (size_t)b * g.sA + (size_t)kp * g.kspan) : nullptr;
  const unsigned short* Bh = g.Bh + (size_t)b * g.sB + (size_t)kp * g.kspan;
  const unsigned short* Bl = SB ? (g.Bl + (size_t)b * g.sB + (size_t)kp * g.kspan) : nullptr;

  f32x4 acc[MF][NF] = {};

  const int kIters = g.kspan / KC;
  for (int kt = 0; kt < kIters; ++kt) {
    const int kb = kt * KC;
#pragma unroll
    for (int r = 0; r < ASZ / (8 * NT); ++r) {
      int idx = tid + r * NT;
      int row = idx >> 3, sl = idx & 7;
      int kc = (sl ^ (row & 7)) << 3;                  // XOR swizzle
      size_t goff = (size_t)(bm * BM + row) * g.lda + kb + kc;
      async16(&ldsAh[idx << 3], Ah + goff);
      if constexpr (SA) async16(&ldsAl[idx << 3], Al + goff);
    }
#pragma unroll
    for (int r = 0; r < BSZ / (8 * NT); ++r) {
      int idx = tid + r * NT;
      int row = idx >> 3, sl = idx & 7;
      int kc = (sl ^ (row & 7)) << 3;
      size_t goff = (size_t)(bn * BN + row) * g.ldb + kb + kc;
      async16(&ldsBh[idx << 3], Bh + goff);
      if constexpr (SB) async16(&ldsBl[idx << 3], Bl + goff);
    }
    __syncthreads();

    const int rsel = lane & 15, kq = lane >> 4;
#pragma unroll
    for (int ks = 0; ks < KC; ks += 32) {
      const int chunk = (ks >> 3) + kq;
      u16x8 afh[MF], afl[MF], bfh[NF], bfl[NF];
#pragma unroll
      for (int fm = 0; fm < MF; ++fm) {
        int row = wm * WM + fm * 16 + rsel;
        int ro = row * KC + ((chunk ^ (row & 7)) << 3);
        afh[fm] = *(const u16x8*)&ldsAh[ro];
        if constexpr (SA) afl[fm] = *(const u16x8*)&ldsAl[ro];
      }
#pragma unroll
      for (int fn = 0; fn < NF; ++fn) {
        int row = wn * WN + fn * 16 + rsel;
        int ro = row * KC + ((chunk ^ (row & 7)) << 3);
        bfh[fn] = *(const u16x8*)&ldsBh[ro];
        if constexpr (SB) bfl[fn] = *(const u16x8*)&ldsBl[ro];
      }
#pragma unroll
      for (int fm = 0; fm < MF; ++fm)
#pragma unroll
        for (int fn = 0; fn < NF; ++fn) {
          acc[fm][fn] = mfma16<F16>(afh[fm], bfh[fn], acc[fm][fn]);
          if constexpr (SB) acc[fm][fn] = mfma16<F16>(afh[fm], bfl[fn], acc[fm][fn]);
          if constexpr (SA) acc[fm][fn] = mfma16<F16>(afl[fm], bfh[fn], acc[fm][fn]);
        }
    }
    __syncthreads();
  }

  if constexpr (EPI == EPI_SPLIT || EPI == EPI_F16) {
    // direct 16-bit scattered stores (small outputs)
#pragma unroll
    for (int fm = 0; fm < MF; ++fm)
#pragma unroll
      for (int fn = 0; fn < NF; ++fn)
#pragma unroll
        for (int r = 0; r < 4; ++r) {
          int i = bm * BM + wm * WM + fm * 16 + ((lane >> 4) << 2) + r;
          int j = bn * BN + wn * WN + fn * 16 + (lane & 15);
          float v = acc[fm][fn][r];
          size_t co = (size_t)z * g.sC + (size_t)i * g.ldc + j;
          if constexpr (EPI == EPI_SPLIT) {
            unsigned short h = f2bf(v);
            g.Ch[co] = h;
            g.Cl[co] = f2bf(v - bf2f(h));
          } else {
            g.Ch[co] = f2h(v);
          }
        }
  } else {
    // Chunked LDS epilogue: 32 rows x BN f32 per chunk, coalesced stores.
    float* eb = (float*)ldsraw;
#pragma unroll
    for (int ck = 0; ck < BM / 32; ++ck) {
      if (wm == (ck * 32) / WM) {
        const int fm0 = ((ck * 32) % WM) / 16;
#pragma unroll
        for (int fi = 0; fi < 2; ++fi) {
          int fm = fm0 + fi;
#pragma unroll
          for (int fn = 0; fn < NF; ++fn)
#pragma unroll
            for (int r = 0; r < 4; ++r) {
              int lrow = fi * 16 + ((lane >> 4) << 2) + r;
              int col = wn * WN + fn * 16 + (lane & 15);
              eb[lrow * EPAD + col] = acc[fm][fn][r];
            }
        }
      }
      __syncthreads();
#pragma unroll
      for (int it = 0; it < (32 * BN / 4) / NT; ++it) {
        int idx = it * NT + tid;
        int row = idx / (BN / 4), c4 = (idx % (BN / 4)) * 4;
        f32x4 v = *(f32x4*)&eb[row * EPAD + c4];
        int grow = bm * BM + ck * 32 + row;
        int j = bn * BN + c4;
        if constexpr (EPI == EPI_OUT) v = v + g.rowv[b * C_ + grow];
        if constexpr (EPI == EPI_DOTS) {
          f32x4 bkv = *(const f32x4*)&g.bk[j];
          f32x4 ksv = *(const f32x4*)&g.colv[b * C_ + j];
          float qsi = g.rowv[b * C_ + grow], bqi = g.bq[grow];
          v = 0.125f * (v + qsi * bkv + bqi * (ksv + 4096.f * bkv));
        }
        *(f32x4*)&g.Cf[(size_t)z * g.sC + (size_t)grow * g.ldc + j] = v;
      }
      __syncthreads();
    }
  }
}

// Fused prep: x tiles (fp32->fp16 Xh + XhT via LDS, row sums) + weight blocks.
#define NXB (64 * 8 * 8)
#define PAD 66
__global__ __launch_bounds__(256) void prep_fused(
    const float* __restrict__ x, const float* __restrict__ Wq,
    const float* __restrict__ Wk, const float* __restrict__ Wv,
    unsigned short* __restrict__ Xh, unsigned short* __restrict__ XhT,
    float* __restrict__ S, unsigned short* Wqh, unsigned short* Wql,
    unsigned short* Wkh, unsigned short* Wkl, unsigned short* WvT) {
  __shared__ unsigned short tile[64 * PAD];
  const int tid = threadIdx.x;
  if (blockIdx.x < NXB) {
    const int tl = blockIdx.x;
    const int t0 = (tl & 63) << 6, c0 = ((tl >> 6) & 7) << 6, b = tl >> 9;
    const float* xin = x + ((size_t)(b * C_ + c0)) * T_ + t0;
    unsigned short* xo = Xh + ((size_t)(b * C_ + c0)) * T_ + t0;
#pragma unroll
    for (int r = 0; r < 4; ++r) {
      int p = tid + r * 256;
      int row = p >> 4, c4 = (p & 15) << 2;
      float4 v = *(const float4*)&xin[(size_t)row * T_ + c4];
      unsigned short h0 = f2h(v.x), h1 = f2h(v.y), h2 = f2h(v.z), h3 = f2h(v.w);
      ushort4 hv; hv.x = h0; hv.y = h1; hv.z = h2; hv.w = h3;
      *(ushort4*)&xo[(size_t)row * T_ + c4] = hv;
      unsigned int lo = (unsigned int)h0 | ((unsigned int)h1 << 16);
      unsigned int hi = (unsigned int)h2 | ((unsigned int)h3 << 16);
      ((unsigned int*)&tile[row * PAD + c4])[0] = lo;
      ((unsigned int*)&tile[row * PAD + c4])[1] = hi;
      float s = v.x + v.y + v.z + v.w;
#pragma unroll
      for (int o = 1; o < 16; o <<= 1) s += __shfl_xor(s, o);
      if ((tid & 15) == 0) atomicAdd(&S[b * C_ + c0 + row], s);
    }
    __syncthreads();
#pragma unroll
    for (int r = 0; r < 2; ++r) {
      int idx = tid + r * 256;
      int trow = idx >> 3, cc = (idx & 7) << 3;
      unsigned short vals[8];
#pragma unroll
      for (int j = 0; j < 8; ++j) vals[j] = tile[(cc + j) * PAD + trow];
      *(uint4*)&XhT[((size_t)b * T_ + t0 + trow) * C_ + c0 + cc] = *(uint4*)vals;
    }
  } else {
    int i = (blockIdx.x - NXB) * 256 + tid;  // 0..C*C-1
    float q = Wq[i]; unsigned short qh = f2bf(q); Wqh[i] = qh; Wql[i] = f2bf(q - bf2f(qh));
    float k = Wk[i]; unsigned short kh = f2bf(k); Wkh[i] = kh; Wkl[i] = f2bf(k - bf2f(kh));
    float v = Wv[i]; int d = i >> 9, e = i & 511;
    WvT[(e << 9) + d] = f2h(v);
  }
}

// G combine: sum 8 splitK partials from the lower-triangle source tile
// (transposing via LDS for mirrored upper tiles) -> bf16 hi/lo full square.
// Grid swizzled so batch = blk%8 -> per-XCD partials L2-resident.
__global__ __launch_bounds__(256) void combine_g(const float* __restrict__ gp,
                                                 unsigned short* __restrict__ gh,
                                                 unsigned short* __restrict__ gl) {
  __shared__ float tile[64 * 65];
  const int blk = blockIdx.x;             // b = blk&7; q = blk>>3 -> 64x64 tiles
  const int b = blk & 7, q = blk >> 3;
  const int tr = q >> 3, tc = q & 7;
  const bool mirror = (tr >> 1) < (tc >> 1);      // containing 128-tile is upper
  const int sr = mirror ? tc : tr, sc = mirror ? tr : tc;
  const float* src = gp + ((size_t)b << 21) + (size_t)(sr << 6) * 512 + (sc << 6);
  const int row = threadIdx.x >> 4, c4 = (threadIdx.x & 15) << 2;
  float vals[4][4];
#pragma unroll
  for (int rr = 0; rr < 4; ++rr) {
    const int r = row + rr * 16;
    f32x4 v = {};
#pragma unroll
    for (int p = 0; p < 8; ++p)
      v += *(const f32x4*)&src[((size_t)p << 18) + (size_t)r * 512 + c4];
    if (mirror) {
#pragma unroll
      for (int k = 0; k < 4; ++k) tile[r * 65 + c4 + k] = v[k];
    } else {
#pragma unroll
      for (int k = 0; k < 4; ++k) vals[rr][k] = v[k];
    }
  }
  if (mirror) {
    __syncthreads();
#pragma unroll
    for (int rr = 0; rr < 4; ++rr) {
      const int r = row + rr * 16;
#pragma unroll
      for (int k = 0; k < 4; ++k) vals[rr][k] = tile[(c4 + k) * 65 + r];
    }
  }
  unsigned short* ghp = gh + ((size_t)b << 18) + (size_t)(tr << 6) * 512 + (tc << 6);
  unsigned short* glp = gl + ((size_t)b << 18) + (size_t)(tr << 6) * 512 + (tc << 6);
#pragma unroll
  for (int rr = 0; rr < 4; ++rr) {
    const int r = row + rr * 16;
    ushort4 h, l;
    h.x = f2bf(vals[rr][0]); l.x = f2bf(vals[rr][0] - bf2f(h.x));
    h.y = f2bf(vals[rr][1]); l.y = f2bf(vals[rr][1] - bf2f(h.y));
    h.z = f2bf(vals[rr][2]); l.z = f2bf(vals[rr][2] - bf2f(h.z));
    h.w = f2bf(vals[rr][3]); l.w = f2bf(vals[rr][3] - bf2f(h.w));
    *(ushort4*)&ghp[(size_t)r * 512 + c4] = h;
    *(ushort4*)&glp[(size_t)r * 512 + c4] = l;
  }
}

// qs[b,i] = sum_c Wq[i,c] s[b,c];  ks[b,i] = sum_c Wk[i,c] s[b,c]
__global__ __launch_bounds__(256) void qs_ks(const float* __restrict__ Wq, const float* __restrict__ Wk,
                                             const float* __restrict__ s, float* __restrict__ qs,
                                             float* __restrict__ ks) {
  int lane = threadIdx.x & 63, wid = threadIdx.x >> 6;
  int gi = blockIdx.x * 4 + wid;
  int b = gi >> 9, i = gi & 511;
  const float* sv = s + (b << 9);
  const float* wqr = Wq + (size_t)i * C_;
  const float* wkr = Wk + (size_t)i * C_;
  float aq = 0.f, ak = 0.f;
#pragma unroll
  for (int c = lane; c < C_; c += 64) {
    float sc = sv[c];
    aq += wqr[c] * sc;
    ak += wkr[c] * sc;
  }
#pragma unroll
  for (int o = 32; o > 0; o >>= 1) { aq += __shfl_down(aq, o); ak += __shfl_down(ak, o); }
  if (lane == 0) { qs[gi] = aq; ks[gi] = ak; }
}

// rowwise softmax over 512 logits; attn fp16; ab[b,c] = sum_d attn*bv[d]
__global__ __launch_bounds__(256) void softmax_rows(const float* __restrict__ logits,
                                                    const float* __restrict__ bv,
                                                    unsigned short* __restrict__ attn,
                                                    float* __restrict__ ab) {
  const int row = blockIdx.x;
  const int tid = threadIdx.x, lane = tid & 63, wid = tid >> 6;
  const float* L = logits + (size_t)row * C_;
  float v0 = L[tid], v1 = L[tid + 256];
  __shared__ float red[4];
  float m = fmaxf(v0, v1);
#pragma unroll
  for (int o = 32; o > 0; o >>= 1) m = fmaxf(m, __shfl_down(m, o));
  if (lane == 0) red[wid] = m;
  __syncthreads();
  m = fmaxf(fmaxf(red[0], red[1]), fmaxf(red[2], red[3]));
  __syncthreads();
  float e0 = __expf(v0 - m), e1 = __expf(v1 - m);
  float sum = e0 + e1;
#pragma unroll
  for (int o = 32; o > 0; o >>= 1) sum += __shfl_down(sum, o);
  if (lane == 0) red[wid] = sum;
  __syncthreads();
  sum = red[0] + red[1] + red[2] + red[3];
  float inv = 1.f / sum;
  float a0 = e0 * inv, a1 = e1 * inv;
  unsigned short* ar = attn + (size_t)row * C_;
  ar[tid] = f2h(a0);
  ar[tid + 256] = f2h(a1);
  float abv = a0 * bv[tid] + a1 * bv[tid + 256];
  __syncthreads();
#pragma unroll
  for (int o = 32; o > 0; o >>= 1) abv += __shfl_down(abv, o);
  if (lane == 0) red[wid] = abv;
  __syncthreads();
  if (tid == 0) ab[row] = red[0] + red[1] + red[2] + red[3];
}

extern "C" void kernel_launch(void* const* d_in, const int* in_sizes, int n_in,
                              void* d_out, int out_size, void* d_ws, size_t ws_size,
                              hipStream_t stream) {
  const float* x  = (const float*)d_in[0];
  const float* Wq = (const float*)d_in[1];
  const float* bq = (const float*)d_in[2];
  const float* Wk = (const float*)d_in[3];
  const float* bk = (const float*)d_in[4];
  const float* Wv = (const float*)d_in[5];
  const float* bv = (const float*)d_in[6];
  float* out = (float*)d_out;

  char* ws = (char*)d_ws;
  size_t off = 0;
  auto alloc = [&](size_t bytes) {
    char* p = ws + off;
    off += (bytes + 255) & ~(size_t)255;
    return p;
  };
  const size_t XSZ = (size_t)B_ * C_ * T_;
  const size_t GSZ = (size_t)B_ * C_ * C_;   // 2^21

  unsigned short* Xh  = (unsigned short*)alloc(XSZ * 2);
  unsigned short* XhT = (unsigned short*)alloc(XSZ * 2);
  float* Gpart = (float*)alloc((size_t)8 * GSZ * 4);   // 67 MB (8 splitK parts)
  unsigned short* Gh = (unsigned short*)alloc(GSZ * 2);
  unsigned short* Gl = (unsigned short*)alloc(GSZ * 2);
  unsigned short* Ph = (unsigned short*)alloc(GSZ * 2);
  unsigned short* Pl = (unsigned short*)alloc(GSZ * 2);
  float* Logits = (float*)alloc(GSZ * 4);
  unsigned short* Attn = (unsigned short*)alloc(GSZ * 2);
  unsigned short* Mh = (unsigned short*)alloc(GSZ * 2);
  unsigned short* Wqh = (unsigned short*)alloc((size_t)C_ * C_ * 2);
  unsigned short* Wql = (unsigned short*)alloc((size_t)C_ * C_ * 2);
  unsigned short* Wkh = (unsigned short*)alloc((size_t)C_ * C_ * 2);
  unsigned short* Wkl = (unsigned short*)alloc((size_t)C_ * C_ * 2);
  unsigned short* WvT = (unsigned short*)alloc((size_t)C_ * C_ * 2);
  float* S  = (float*)alloc((size_t)B_ * C_ * 4);
  float* Qs = (float*)alloc((size_t)B_ * C_ * 4);
  float* Ks = (float*)alloc((size_t)B_ * C_ * 4);
  float* Ab = (float*)alloc((size_t)B_ * C_ * 4);

  hipMemsetAsync(S, 0, (size_t)B_ * C_ * 4, stream);
  prep_fused<<<NXB + C_ * C_ / 256, 256, 0, stream>>>(x, Wq, Wk, Wv, Xh, XhT, S,
                                                      Wqh, Wql, Wkh, Wkl, WvT);
  qs_ks<<<B_ * C_ / 4, 256, 0, stream>>>(Wq, Wk, S, Qs, Ks);

  {  // G = X X^T, fp16, lower-triangle 128-tiles, splitK=8, XCD-swizzled
    GemmP p = {};
    p.Ah = Xh; p.sA = (long)C_ * T_; p.lda = T_;
    p.Bh = Xh; p.sB = (long)C_ * T_; p.ldb = T_;
    p.Cf = Gpart; p.sC = (long)C_ * C_; p.ldc = C_;
    p.kspan = T_ / 8; p.zparts = 8;
    gemm_nt<128, 128, 32, 64, false, false, EPI_F32, true, 1>
        <<<640, 512, 0, stream>>>(p);
  }
  combine_g<<<B_ * 64, 256, 0, stream>>>(Gpart, Gh, Gl);

  {  // P = Wq G (bf16 hi/lo 3-pass), direct split output
    GemmP p = {};
    p.Ah = Wqh; p.Al = Wql; p.sA = 0; p.lda = C_;
    p.Bh = Gh; p.Bl = Gl; p.sB = (long)C_ * C_; p.ldb = C_;
    p.Ch = Ph; p.Cl = Pl; p.sC = (long)C_ * C_; p.ldc = C_;
    p.kspan = C_; p.zparts = 1;
    gemm_nt<64, 64, 32, 32, true, true, EPI_SPLIT, false, 0>
        <<<dim3(8, 8, 8), 256, 0, stream>>>(p);
  }
  {  // logits = 0.125*(P Wk^T + rank-1 bias terms), fp32, LDS-staged stores
    GemmP p = {};
    p.Ah = Ph; p.Al = Pl; p.sA = (long)C_ * C_; p.lda = C_;
    p.Bh = Wkh; p.Bl = Wkl; p.sB = 0; p.ldb = C_;
    p.Cf = Logits; p.sC = (long)C_ * C_; p.ldc = C_;
    p.kspan = C_; p.zparts = 1;
    p.rowv = Qs; p.colv = Ks; p.bq = bq; p.bk = bk;
    gemm_nt<64, 64, 32, 32, true, true, EPI_DOTS, false, 0>
        <<<dim3(8, 8, 8), 256, 0, stream>>>(p);
  }
  softmax_rows<<<B_ * C_, 256, 0, stream>>>(Logits, bv, Attn, Ab);
  {  // M = attn Wv (fp16, NT with WvT), direct fp16 output
    GemmP p = {};
    p.Ah = Attn; p.sA = (long)C_ * C_; p.lda = C_;
    p.Bh = WvT; p.sB = 0; p.ldb = C_;
    p.Ch = Mh; p.sC = (long)C_ * C_; p.ldc = C_;
    p.kspan = C_; p.zparts = 1;
    gemm_nt<64, 64, 32, 32, false, false, EPI_F16, true, 0>
        <<<dim3(8, 8, 8), 256, 0, stream>>>(p);
  }
  {  // out = M X + ab (fp16, NT with XhT), 128x256 8-wave, XCD-swizzled
    GemmP p = {};
    p.Ah = Mh; p.sA = (long)C_ * C_; p.lda = C_;
    p.Bh = XhT; p.sB = (long)C_ * T_; p.ldb = C_;
    p.Cf = out; p.sC = (long)C_ * T_; p.ldc = T_;
    p.kspan = C_; p.zparts = 1;
    p.rowv = Ab;
    gemm_nt<128, 256, 64, 64, false, false, EPI_OUT, true, 2>
        <<<512, 512, 0, stream>>>(p);
  }
  (void)in_sizes; (void)n_in; (void)out_size; (void)ws_size;
}

// Round 7
// 231.328 us; speedup vs baseline: 1.4520x; 1.0115x over previous
//
#include <hip/hip_runtime.h>

#define B_ 8
#define C_ 512
#define T_ 4096

typedef __attribute__((ext_vector_type(8))) __bf16 bf16x8;
typedef __attribute__((ext_vector_type(8))) _Float16 f16x8;
typedef __attribute__((ext_vector_type(8))) unsigned short u16x8;
typedef __attribute__((ext_vector_type(4))) float f32x4;

__device__ __forceinline__ unsigned short f2bf(float f) {
  unsigned int u = __float_as_uint(f);
  u += 0x7fffu + ((u >> 16) & 1u);   // RNE
  return (unsigned short)(u >> 16);
}
__device__ __forceinline__ float bf2f(unsigned short h) {
  return __uint_as_float(((unsigned int)h) << 16);
}
__device__ __forceinline__ unsigned short f2h(float f) {
  return __builtin_bit_cast(unsigned short, (_Float16)f);
}

__device__ __forceinline__ void async16(unsigned short* ldsdst, const unsigned short* gsrc) {
  __builtin_amdgcn_global_load_lds(
      (__attribute__((address_space(1))) void*)(void*)const_cast<unsigned short*>(gsrc),
      (__attribute__((address_space(3))) void*)(void*)ldsdst,
      16, 0, 0);
}

template <bool F16>
__device__ __forceinline__ f32x4 mfma16(u16x8 a, u16x8 b, f32x4 c) {
  if constexpr (F16)
    return __builtin_amdgcn_mfma_f32_16x16x32_f16(
        __builtin_bit_cast(f16x8, a), __builtin_bit_cast(f16x8, b), c, 0, 0, 0);
  else
    return __builtin_amdgcn_mfma_f32_16x16x32_bf16(
        __builtin_bit_cast(bf16x8, a), __builtin_bit_cast(bf16x8, b), c, 0, 0, 0);
}

struct GemmP {
  const unsigned short* Ah; const unsigned short* Al; long sA; int lda;
  const unsigned short* Bh; const unsigned short* Bl; long sB; int ldb;
  float* Cf; unsigned short* Ch; unsigned short* Cl; long sC; int ldc;
  int kspan; int zparts;
  const float* rowv; const float* colv; const float* bq; const float* bk;
};

enum { EPI_F32 = 0, EPI_OUT = 1, EPI_DOTS = 2, EPI_SPLIT = 3, EPI_F16 = 4 };
// SWZ: 0 = 3D grid (x,y,z); 1 = G-triangle linear grid, kp%8 -> XCD;
//      2 = out linear grid, T-tile%8 -> XCD.

// NT GEMM: C[i][j] = sum_k A[i][k]*B[j][k]; optional hi/lo split (3-pass).
// KC=64, XOR-swizzled 16B chunks (conflict-free ds_read_b128 + legal
// global_load_lds). f32 epilogues staged via LDS, stored non-temporally
// (write-once streams; keep L2 for the 16-bit operands).
template <int BM, int BN, int WM, int WN, bool SA, bool SB, int EPI, bool F16, int SWZ>
__global__ __launch_bounds__((BM / WM) * (BN / WN) * 64) void gemm_nt(GemmP g) {
  constexpr int KC = 64;
  constexpr int NWAVE = (BM / WM) * (BN / WN);
  constexpr int NT = NWAVE * 64;
  constexpr int ASZ = BM * KC, BSZ = BN * KC;
  constexpr int STAGE = (SA ? 2 : 1) * ASZ + (SB ? 2 : 1) * BSZ;  // shorts
  constexpr int EPAD = BN + 4;
  constexpr int EPIB = 32 * EPAD * 4;                              // bytes
  constexpr int LDSB = (STAGE * 2 > EPIB) ? STAGE * 2 : EPIB;
  __shared__ alignas(16) char ldsraw[LDSB];
  unsigned short* lds = (unsigned short*)ldsraw;
  unsigned short* ldsAh = lds;
  unsigned short* ldsAl = lds + ASZ;
  unsigned short* ldsBh = lds + (SA ? 2 : 1) * ASZ;
  unsigned short* ldsBl = ldsBh + BSZ;

  const int tid = threadIdx.x;
  const int lane = tid & 63, wid = tid >> 6;
  constexpr int WNB = BN / WN;
  const int wm = wid / WNB, wn = wid % WNB;
  constexpr int MF = WM / 16, NF = WN / 16;

  int bm, bn, z;
  if constexpr (SWZ == 1) {
    const int blk = blockIdx.x;
    const int r = blk & 7, q = blk >> 3;       // q 0..79
    const int tri = q % 10, zq = q / 10;
    const int tm = (tri >= 6) ? 3 : (tri >= 3) ? 2 : (tri >= 1) ? 1 : 0;
    bm = tm; bn = tri - (tm * (tm + 1)) / 2;
    z = zq * 8 + r;                            // b = zq, kp = r
  } else if constexpr (SWZ == 2) {
    const int blk = blockIdx.x;
    const int r = blk & 7, q = blk >> 3;       // q 0..63
    bm = q & 3;
    const int w = q >> 2;                      // 0..15
    bn = ((w & 1) << 3) + r;                   // 0..15
    z = w >> 1;                                // batch 0..7
  } else {
    bm = blockIdx.x; bn = blockIdx.y; z = blockIdx.z;
  }
  const int b = z / g.zparts, kp = z - b * g.zparts;

  const unsigned short* Ah = g.Ah + (size_t)b * g.sA + (size_t)kp * g.kspan;
  const unsigned short* Al = SA ? (g.Al + (size_t)b * g.sA + (size_t)kp * g.kspan) : nullptr;
  const unsigned short* Bh = g.Bh + (size_t)b * g.sB + (size_t)kp * g.kspan;
  const unsigned short* Bl = SB ? (g.Bl + (size_t)b * g.sB + (size_t)kp * g.kspan) : nullptr;

  f32x4 acc[MF][NF] = {};

  const int kIters = g.kspan / KC;
  for (int kt = 0; kt < kIters; ++kt) {
    const int kb = kt * KC;
#pragma unroll
    for (int r = 0; r < ASZ / (8 * NT); ++r) {
      int idx = tid + r * NT;
      int row = idx >> 3, sl = idx & 7;
      int kc = (sl ^ (row & 7)) << 3;                  // XOR swizzle
      size_t goff = (size_t)(bm * BM + row) * g.lda + kb + kc;
      async16(&ldsAh[idx << 3], Ah + goff);
      if constexpr (SA) async16(&ldsAl[idx << 3], Al + goff);
    }
#pragma unroll
    for (int r = 0; r < BSZ / (8 * NT); ++r) {
      int idx = tid + r * NT;
      int row = idx >> 3, sl = idx & 7;
      int kc = (sl ^ (row & 7)) << 3;
      size_t goff = (size_t)(bn * BN + row) * g.ldb + kb + kc;
      async16(&ldsBh[idx << 3], Bh + goff);
      if constexpr (SB) async16(&ldsBl[idx << 3], Bl + goff);
    }
    __syncthreads();

    const int rsel = lane & 15, kq = lane >> 4;
#pragma unroll
    for (int ks = 0; ks < KC; ks += 32) {
      const int chunk = (ks >> 3) + kq;
      u16x8 afh[MF], afl[MF], bfh[NF], bfl[NF];
#pragma unroll
      for (int fm = 0; fm < MF; ++fm) {
        int row = wm * WM + fm * 16 + rsel;
        int ro = row * KC + ((chunk ^ (row & 7)) << 3);
        afh[fm] = *(const u16x8*)&ldsAh[ro];
        if constexpr (SA) afl[fm] = *(const u16x8*)&ldsAl[ro];
      }
#pragma unroll
      for (int fn = 0; fn < NF; ++fn) {
        int row = wn * WN + fn * 16 + rsel;
        int ro = row * KC + ((chunk ^ (row & 7)) << 3);
        bfh[fn] = *(const u16x8*)&ldsBh[ro];
        if constexpr (SB) bfl[fn] = *(const u16x8*)&ldsBl[ro];
      }
#pragma unroll
      for (int fm = 0; fm < MF; ++fm)
#pragma unroll
        for (int fn = 0; fn < NF; ++fn) {
          acc[fm][fn] = mfma16<F16>(afh[fm], bfh[fn], acc[fm][fn]);
          if constexpr (SB) acc[fm][fn] = mfma16<F16>(afh[fm], bfl[fn], acc[fm][fn]);
          if constexpr (SA) acc[fm][fn] = mfma16<F16>(afl[fm], bfh[fn], acc[fm][fn]);
        }
    }
    __syncthreads();
  }

  if constexpr (EPI == EPI_SPLIT || EPI == EPI_F16) {
#pragma unroll
    for (int fm = 0; fm < MF; ++fm)
#pragma unroll
      for (int fn = 0; fn < NF; ++fn)
#pragma unroll
        for (int r = 0; r < 4; ++r) {
          int i = bm * BM + wm * WM + fm * 16 + ((lane >> 4) << 2) + r;
          int j = bn * BN + wn * WN + fn * 16 + (lane & 15);
          float v = acc[fm][fn][r];
          size_t co = (size_t)z * g.sC + (size_t)i * g.ldc + j;
          if constexpr (EPI == EPI_SPLIT) {
            unsigned short h = f2bf(v);
            g.Ch[co] = h;
            g.Cl[co] = f2bf(v - bf2f(h));
          } else {
            g.Ch[co] = f2h(v);
          }
        }
  } else {
    // Chunked LDS epilogue: 32 rows x BN f32 per chunk, coalesced nt stores.
    float* eb = (float*)ldsraw;
#pragma unroll
    for (int ck = 0; ck < BM / 32; ++ck) {
      if (wm == (ck * 32) / WM) {
        const int fm0 = ((ck * 32) % WM) / 16;
#pragma unroll
        for (int fi = 0; fi < 2; ++fi) {
          int fm = fm0 + fi;
#pragma unroll
          for (int fn = 0; fn < NF; ++fn)
#pragma unroll
            for (int r = 0; r < 4; ++r) {
              int lrow = fi * 16 + ((lane >> 4) << 2) + r;
              int col = wn * WN + fn * 16 + (lane & 15);
              eb[lrow * EPAD + col] = acc[fm][fn][r];
            }
        }
      }
      __syncthreads();
#pragma unroll
      for (int it = 0; it < (32 * BN / 4) / NT; ++it) {
        int idx = it * NT + tid;
        int row = idx / (BN / 4), c4 = (idx % (BN / 4)) * 4;
        f32x4 v = *(f32x4*)&eb[row * EPAD + c4];
        int grow = bm * BM + ck * 32 + row;
        int j = bn * BN + c4;
        if constexpr (EPI == EPI_OUT) v = v + g.rowv[b * C_ + grow];
        if constexpr (EPI == EPI_DOTS) {
          f32x4 bkv = *(const f32x4*)&g.bk[j];
          f32x4 ksv = *(const f32x4*)&g.colv[b * C_ + j];
          float qsi = g.rowv[b * C_ + grow], bqi = g.bq[grow];
          v = 0.125f * (v + qsi * bkv + bqi * (ksv + 4096.f * bkv));
        }
        __builtin_nontemporal_store(
            v, (f32x4*)&g.Cf[(size_t)z * g.sC + (size_t)grow * g.ldc + j]);
      }
      __syncthreads();
    }
  }
}

// Fused prep: x blocks 64c x 256t, software-pipelined sub-tiles (loads for
// sub-tile st+1 issued before st's transpose barrier) -> Xh + XhT; no sums.
// Weight blocks: Wq/Wk -> bf16 hi/lo, Wv -> transposed fp16.
#define NXB2 1024
#define PAD 66
__global__ __launch_bounds__(256) void prep_fused(
    const float* __restrict__ x, const float* __restrict__ Wq,
    const float* __restrict__ Wk, const float* __restrict__ Wv,
    unsigned short* __restrict__ Xh, unsigned short* __restrict__ XhT,
    unsigned short* Wqh, unsigned short* Wql,
    unsigned short* Wkh, unsigned short* Wkl, unsigned short* WvT) {
  __shared__ unsigned short tile[64 * PAD];
  const int tid = threadIdx.x;
  if (blockIdx.x < NXB2) {
    const int tl = blockIdx.x;
    const int tb = tl & 15, c0 = ((tl >> 4) & 7) << 6, b = tl >> 7;
    const int t0 = tb << 8;
    const float* xin = x + ((size_t)(b * C_ + c0)) * T_ + t0;
    unsigned short* xo = Xh + ((size_t)(b * C_ + c0)) * T_ + t0;
    const int row16 = tid >> 4, c4 = (tid & 15) << 2;
    float4 v[4];
#pragma unroll
    for (int r = 0; r < 4; ++r)
      v[r] = *(const float4*)&xin[(size_t)(row16 + r * 16) * T_ + c4];
    for (int st = 0; st < 4; ++st) {
      if (st) __syncthreads();
#pragma unroll
      for (int r = 0; r < 4; ++r) {
        int row = row16 + r * 16;
        unsigned short h0 = f2h(v[r].x), h1 = f2h(v[r].y),
                       h2 = f2h(v[r].z), h3 = f2h(v[r].w);
        ushort4 hv; hv.x = h0; hv.y = h1; hv.z = h2; hv.w = h3;
        *(ushort4*)&xo[(size_t)row * T_ + st * 64 + c4] = hv;
        unsigned int lo = (unsigned int)h0 | ((unsigned int)h1 << 16);
        unsigned int hi = (unsigned int)h2 | ((unsigned int)h3 << 16);
        ((unsigned int*)&tile[row * PAD + c4])[0] = lo;
        ((unsigned int*)&tile[row * PAD + c4])[1] = hi;
      }
      float4 nv[4];
      if (st < 3) {
#pragma unroll
        for (int r = 0; r < 4; ++r)
          nv[r] = *(const float4*)&xin[(size_t)(row16 + r * 16) * T_ + (st + 1) * 64 + c4];
      }
      __syncthreads();
#pragma unroll
      for (int r = 0; r < 2; ++r) {
        int idx = tid + r * 256;
        int trow = idx >> 3, cc = (idx & 7) << 3;
        unsigned short vals[8];
#pragma unroll
        for (int j = 0; j < 8; ++j) vals[j] = tile[(cc + j) * PAD + trow];
        *(uint4*)&XhT[((size_t)b * T_ + t0 + st * 64 + trow) * C_ + c0 + cc] =
            *(uint4*)vals;
      }
#pragma unroll
      for (int r = 0; r < 4; ++r) v[r] = nv[r];
    }
  } else {
    int i = (blockIdx.x - NXB2) * 256 + tid;  // 0..C*C-1
    float q = Wq[i]; unsigned short qh = f2bf(q); Wqh[i] = qh; Wql[i] = f2bf(q - bf2f(qh));
    float k = Wk[i]; unsigned short kh = f2bf(k); Wkh[i] = kh; Wkl[i] = f2bf(k - bf2f(kh));
    float v = Wv[i]; int d = i >> 9, e = i & 511;
    WvT[(e << 9) + d] = f2h(v);
  }
}

// S[b,c] = sum_t Xh[b,c,t]  (one wave per row)
__global__ __launch_bounds__(256) void sum_rows(const unsigned short* __restrict__ xh,
                                                float* __restrict__ S) {
  const int row = blockIdx.x * 4 + (threadIdx.x >> 6);
  const int lane = threadIdx.x & 63;
  const unsigned short* r = xh + (size_t)row * T_;
  float s = 0.f;
#pragma unroll
  for (int i = 0; i < 8; ++i) {
    f16x8 v = *(const f16x8*)&r[(i * 64 + lane) * 8];
#pragma unroll
    for (int j = 0; j < 8; ++j) s += (float)v[j];
  }
#pragma unroll
  for (int o = 32; o > 0; o >>= 1) s += __shfl_down(s, o);
  if (lane == 0) S[row] = s;
}

// G combine: sum 8 splitK partials from the lower-triangle source tile
// (transposing via LDS for mirrored upper tiles) -> bf16 hi/lo full square.
__global__ __launch_bounds__(256) void combine_g(const float* __restrict__ gp,
                                                 unsigned short* __restrict__ gh,
                                                 unsigned short* __restrict__ gl) {
  __shared__ float tile[64 * 65];
  const int blk = blockIdx.x;             // b = blk&7; q = blk>>3 -> 64x64 tiles
  const int b = blk & 7, q = blk >> 3;
  const int tr = q >> 3, tc = q & 7;
  const bool mirror = (tr >> 1) < (tc >> 1);      // containing 128-tile is upper
  const int sr = mirror ? tc : tr, sc = mirror ? tr : tc;
  const float* src = gp + ((size_t)b << 21) + (size_t)(sr << 6) * 512 + (sc << 6);
  const int row = threadIdx.x >> 4, c4 = (threadIdx.x & 15) << 2;
  float vals[4][4];
#pragma unroll
  for (int rr = 0; rr < 4; ++rr) {
    const int r = row + rr * 16;
    f32x4 v = {};
#pragma unroll
    for (int p = 0; p < 8; ++p)
      v += __builtin_nontemporal_load(
          (const f32x4*)&src[((size_t)p << 18) + (size_t)r * 512 + c4]);
    if (mirror) {
#pragma unroll
      for (int k = 0; k < 4; ++k) tile[r * 65 + c4 + k] = v[k];
    } else {
#pragma unroll
      for (int k = 0; k < 4; ++k) vals[rr][k] = v[k];
    }
  }
  if (mirror) {
    __syncthreads();
#pragma unroll
    for (int rr = 0; rr < 4; ++rr) {
      const int r = row + rr * 16;
#pragma unroll
      for (int k = 0; k < 4; ++k) vals[rr][k] = tile[(c4 + k) * 65 + r];
    }
  }
  unsigned short* ghp = gh + ((size_t)b << 18) + (size_t)(tr << 6) * 512 + (tc << 6);
  unsigned short* glp = gl + ((size_t)b << 18) + (size_t)(tr << 6) * 512 + (tc << 6);
#pragma unroll
  for (int rr = 0; rr < 4; ++rr) {
    const int r = row + rr * 16;
    ushort4 h, l;
    h.x = f2bf(vals[rr][0]); l.x = f2bf(vals[rr][0] - bf2f(h.x));
    h.y = f2bf(vals[rr][1]); l.y = f2bf(vals[rr][1] - bf2f(h.y));
    h.z = f2bf(vals[rr][2]); l.z = f2bf(vals[rr][2] - bf2f(h.z));
    h.w = f2bf(vals[rr][3]); l.w = f2bf(vals[rr][3] - bf2f(h.w));
    *(ushort4*)&ghp[(size_t)r * 512 + c4] = h;
    *(ushort4*)&glp[(size_t)r * 512 + c4] = l;
  }
}

// qs[b,i] = sum_c Wq[i,c] s[b,c];  ks[b,i] = sum_c Wk[i,c] s[b,c]
__global__ __launch_bounds__(256) void qs_ks(const float* __restrict__ Wq, const float* __restrict__ Wk,
                                             const float* __restrict__ s, float* __restrict__ qs,
                                             float* __restrict__ ks) {
  int lane = threadIdx.x & 63, wid = threadIdx.x >> 6;
  int gi = blockIdx.x * 4 + wid;
  int b = gi >> 9, i = gi & 511;
  const float* sv = s + (b << 9);
  const float* wqr = Wq + (size_t)i * C_;
  const float* wkr = Wk + (size_t)i * C_;
  float aq = 0.f, ak = 0.f;
#pragma unroll
  for (int c = lane; c < C_; c += 64) {
    float sc = sv[c];
    aq += wqr[c] * sc;
    ak += wkr[c] * sc;
  }
#pragma unroll
  for (int o = 32; o > 0; o >>= 1) { aq += __shfl_down(aq, o); ak += __shfl_down(ak, o); }
  if (lane == 0) { qs[gi] = aq; ks[gi] = ak; }
}

// rowwise softmax over 512 logits; attn fp16; ab[b,c] = sum_d attn*bv[d]
__global__ __launch_bounds__(256) void softmax_rows(const float* __restrict__ logits,
                                                    const float* __restrict__ bv,
                                                    unsigned short* __restrict__ attn,
                                                    float* __restrict__ ab) {
  const int row = blockIdx.x;
  const int tid = threadIdx.x, lane = tid & 63, wid = tid >> 6;
  const float* L = logits + (size_t)row * C_;
  float v0 = L[tid], v1 = L[tid + 256];
  __shared__ float red[4];
  float m = fmaxf(v0, v1);
#pragma unroll
  for (int o = 32; o > 0; o >>= 1) m = fmaxf(m, __shfl_down(m, o));
  if (lane == 0) red[wid] = m;
  __syncthreads();
  m = fmaxf(fmaxf(red[0], red[1]), fmaxf(red[2], red[3]));
  __syncthreads();
  float e0 = __expf(v0 - m), e1 = __expf(v1 - m);
  float sum = e0 + e1;
#pragma unroll
  for (int o = 32; o > 0; o >>= 1) sum += __shfl_down(sum, o);
  if (lane == 0) red[wid] = sum;
  __syncthreads();
  sum = red[0] + red[1] + red[2] + red[3];
  float inv = 1.f / sum;
  float a0 = e0 * inv, a1 = e1 * inv;
  unsigned short* ar = attn + (size_t)row * C_;
  ar[tid] = f2h(a0);
  ar[tid + 256] = f2h(a1);
  float abv = a0 * bv[tid] + a1 * bv[tid + 256];
  __syncthreads();
#pragma unroll
  for (int o = 32; o > 0; o >>= 1) abv += __shfl_down(abv, o);
  if (lane == 0) red[wid] = abv;
  __syncthreads();
  if (tid == 0) ab[row] = red[0] + red[1] + red[2] + red[3];
}

extern "C" void kernel_launch(void* const* d_in, const int* in_sizes, int n_in,
                              void* d_out, int out_size, void* d_ws, size_t ws_size,
                              hipStream_t stream) {
  const float* x  = (const float*)d_in[0];
  const float* Wq = (const float*)d_in[1];
  const float* bq = (const float*)d_in[2];
  const float* Wk = (const float*)d_in[3];
  const float* bk = (const float*)d_in[4];
  const float* Wv = (const float*)d_in[5];
  const float* bv = (const float*)d_in[6];
  float* out = (float*)d_out;

  char* ws = (char*)d_ws;
  size_t off = 0;
  auto alloc = [&](size_t bytes) {
    char* p = ws + off;
    off += (bytes + 255) & ~(size_t)255;
    return p;
  };
  const size_t XSZ = (size_t)B_ * C_ * T_;
  const size_t GSZ = (size_t)B_ * C_ * C_;   // 2^21

  unsigned short* Xh  = (unsigned short*)alloc(XSZ * 2);
  unsigned short* XhT = (unsigned short*)alloc(XSZ * 2);
  float* Gpart = (float*)alloc((size_t)8 * GSZ * 4);   // 67 MB (8 splitK parts)
  unsigned short* Gh = (unsigned short*)alloc(GSZ * 2);
  unsigned short* Gl = (unsigned short*)alloc(GSZ * 2);
  unsigned short* Ph = (unsigned short*)alloc(GSZ * 2);
  unsigned short* Pl = (unsigned short*)alloc(GSZ * 2);
  float* Logits = (float*)alloc(GSZ * 4);
  unsigned short* Attn = (unsigned short*)alloc(GSZ * 2);
  unsigned short* Mh = (unsigned short*)alloc(GSZ * 2);
  unsigned short* Wqh = (unsigned short*)alloc((size_t)C_ * C_ * 2);
  unsigned short* Wql = (unsigned short*)alloc((size_t)C_ * C_ * 2);
  unsigned short* Wkh = (unsigned short*)alloc((size_t)C_ * C_ * 2);
  unsigned short* Wkl = (unsigned short*)alloc((size_t)C_ * C_ * 2);
  unsigned short* WvT = (unsigned short*)alloc((size_t)C_ * C_ * 2);
  float* S  = (float*)alloc((size_t)B_ * C_ * 4);
  float* Qs = (float*)alloc((size_t)B_ * C_ * 4);
  float* Ks = (float*)alloc((size_t)B_ * C_ * 4);
  float* Ab = (float*)alloc((size_t)B_ * C_ * 4);

  prep_fused<<<NXB2 + C_ * C_ / 256, 256, 0, stream>>>(x, Wq, Wk, Wv, Xh, XhT,
                                                       Wqh, Wql, Wkh, Wkl, WvT);
  sum_rows<<<B_ * C_ / 4, 256, 0, stream>>>(Xh, S);
  qs_ks<<<B_ * C_ / 4, 256, 0, stream>>>(Wq, Wk, S, Qs, Ks);

  {  // G = X X^T, fp16, lower-triangle 128-tiles, splitK=8, XCD-swizzled
    GemmP p = {};
    p.Ah = Xh; p.sA = (long)C_ * T_; p.lda = T_;
    p.Bh = Xh; p.sB = (long)C_ * T_; p.ldb = T_;
    p.Cf = Gpart; p.sC = (long)C_ * C_; p.ldc = C_;
    p.kspan = T_ / 8; p.zparts = 8;
    gemm_nt<128, 128, 32, 64, false, false, EPI_F32, true, 1>
        <<<640, 512, 0, stream>>>(p);
  }
  combine_g<<<B_ * 64, 256, 0, stream>>>(Gpart, Gh, Gl);

  {  // P = Wq G (bf16 hi/lo 3-pass), direct split output
    GemmP p = {};
    p.Ah = Wqh; p.Al = Wql; p.sA = 0; p.lda = C_;
    p.Bh = Gh; p.Bl = Gl; p.sB = (long)C_ * C_; p.ldb = C_;
    p.Ch = Ph; p.Cl = Pl; p.sC = (long)C_ * C_; p.ldc = C_;
    p.kspan = C_; p.zparts = 1;
    gemm_nt<64, 64, 32, 32, true, true, EPI_SPLIT, false, 0>
        <<<dim3(8, 8, 8), 256, 0, stream>>>(p);
  }
  {  // logits = 0.125*(P Wk^T + rank-1 bias terms), fp32 nt stores
    GemmP p = {};
    p.Ah = Ph; p.Al = Pl; p.sA = (long)C_ * C_; p.lda = C_;
    p.Bh = Wkh; p.Bl = Wkl; p.sB = 0; p.ldb = C_;
    p.Cf = Logits; p.sC = (long)C_ * C_; p.ldc = C_;
    p.kspan = C_; p.zparts = 1;
    p.rowv = Qs; p.colv = Ks; p.bq = bq; p.bk = bk;
    gemm_nt<64, 64, 32, 32, true, true, EPI_DOTS, false, 0>
        <<<dim3(8, 8, 8), 256, 0, stream>>>(p);
  }
  softmax_rows<<<B_ * C_, 256, 0, stream>>>(Logits, bv, Attn, Ab);
  {  // M = attn Wv (fp16, NT with WvT), direct fp16 output
    GemmP p = {};
    p.Ah = Attn; p.sA = (long)C_ * C_; p.lda = C_;
    p.Bh = WvT; p.sB = 0; p.ldb = C_;
    p.Ch = Mh; p.sC = (long)C_ * C_; p.ldc = C_;
    p.kspan = C_; p.zparts = 1;
    gemm_nt<64, 64, 32, 32, false, false, EPI_F16, true, 0>
        <<<dim3(8, 8, 8), 256, 0, stream>>>(p);
  }
  {  // out = M X + ab (fp16, NT with XhT), 128x256 8-wave, XCD-swizzled
    GemmP p = {};
    p.Ah = Mh; p.sA = (long)C_ * C_; p.lda = C_;
    p.Bh = XhT; p.sB = (long)C_ * T_; p.ldb = C_;
    p.Cf = out; p.sC = (long)C_ * T_; p.ldc = T_;
    p.kspan = C_; p.zparts = 1;
    p.rowv = Ab;
    gemm_nt<128, 256, 64, 64, false, false, EPI_OUT, true, 2>
        <<<512, 512, 0, stream>>>(p);
  }
  (void)in_sizes; (void)n_in; (void)out_size; (void)ws_size;
}